// Round 7
// baseline (943.633 us; speedup 1.0000x reference)
//
#include <hip/hip_runtime.h>
#include <cstdint>

typedef unsigned short u16;
typedef __bf16 bf16x8 __attribute__((ext_vector_type(8)));
typedef float f32x4 __attribute__((ext_vector_type(4)));
typedef float f32x16 __attribute__((ext_vector_type(16)));

#define M_TOT 8192      // B*S
#define D_IN  4096
#define Z_DIM 1024
#define D_OUT 4096
#define K_CAT 5120      // Z + D_IN

struct alignas(8) u16x4 { u16 x, y, z, w; };

__device__ __forceinline__ u16 to_bf16(float f) {
    union { float f; uint32_t u; } v; v.f = f;
    uint32_t u = v.u;
    // round-to-nearest-even
    uint32_t r = (u + 0x7FFFu + ((u >> 16) & 1u)) >> 16;
    return (u16)r;
}

__device__ __forceinline__ void async_load16(const void* g, void* l) {
    __builtin_amdgcn_global_load_lds(
        (const __attribute__((address_space(1))) void*)g,
        (__attribute__((address_space(3))) void*)l,
        16, 0, 0);
}

// ---------------------------------------------------------------------------
// GEMM (legacy 128x128 / BK=32 / 256-thread structure) — kept for the two
// N=1024 single GEMMs where a 256-tile grid would leave half the CUs idle.
// ---------------------------------------------------------------------------
__global__ __launch_bounds__(256)
void gemm_bt(const u16* __restrict__ A,
             const u16* __restrict__ Bw0, const u16* __restrict__ Bw1,
             const float* __restrict__ bias0, const float* __restrict__ bias1,
             float* __restrict__ C0, float* __restrict__ C1,
             int M, int N, int K)
{
    const u16*  Bw   = blockIdx.z ? Bw1   : Bw0;
    const float* bias = blockIdx.z ? bias1 : bias0;
    float*       C    = blockIdx.z ? C1    : C0;

    __shared__ u16 As[128 * 32];
    __shared__ u16 Bs[128 * 32];

    const int tid  = threadIdx.x;
    const int wave = tid >> 6;
    const int lane = tid & 63;
    const int m0 = blockIdx.y * 128;
    const int n0 = blockIdx.x * 128;
    const int wm = (wave & 1) * 64;
    const int wn = (wave >> 1) * 64;

    const int srow = wave * 32 + (lane >> 2);
    const int scol = (((lane & 3) ^ ((srow >> 1) & 3))) * 8;
    const long long a_off = (long long)(m0 + srow) * K + scol;
    const long long b_off = (long long)(n0 + srow) * K + scol;

    const int fr = lane & 15;   // fragment row/col
    const int fq = lane >> 4;   // quad
    const int rc = (fq ^ ((fr >> 1) & 3)) * 8;

    f32x4 acc[4][4] = {};

    for (int k0 = 0; k0 < K; k0 += 32) {
        async_load16(A  + a_off + k0,            &As[(wave * 32 +  0) * 32]);
        async_load16(A  + a_off + k0 + 16LL * K, &As[(wave * 32 + 16) * 32]);
        async_load16(Bw + b_off + k0,            &Bs[(wave * 32 +  0) * 32]);
        async_load16(Bw + b_off + k0 + 16LL * K, &Bs[(wave * 32 + 16) * 32]);
        __syncthreads();

        bf16x8 af[4], bf[4];
        #pragma unroll
        for (int i = 0; i < 4; i++)
            af[i] = *(const bf16x8*)&As[(wm + i * 16 + fr) * 32 + rc];
        #pragma unroll
        for (int i = 0; i < 4; i++)
            bf[i] = *(const bf16x8*)&Bs[(wn + i * 16 + fr) * 32 + rc];

        #pragma unroll
        for (int mi = 0; mi < 4; mi++)
            #pragma unroll
            for (int ni = 0; ni < 4; ni++)
                acc[mi][ni] = __builtin_amdgcn_mfma_f32_16x16x32_bf16(
                    af[mi], bf[ni], acc[mi][ni], 0, 0, 0);
        __syncthreads();
    }

    #pragma unroll
    for (int ni = 0; ni < 4; ni++) {
        const int col = n0 + wn + ni * 16 + fr;
        const float bv = bias[col];
        #pragma unroll
        for (int mi = 0; mi < 4; mi++) {
            const int row = m0 + wm + mi * 16 + fq * 4;
            float* cp = C + (long long)row * N + col;
            #pragma unroll
            for (int r = 0; r < 4; r++)
                cp[(long long)r * N] = acc[mi][ni][r] + bv;
        }
    }
}

// ---------------------------------------------------------------------------
// 256x256-tile 8-phase GEMM, rev 7: 32x32x16 MFMA shape.
//
// Rev 6 (16x16x32) measured 314us / MfmaUtil 47.5%: per K-tile per CU, LDS
// drain (~565cy/phase) + MFMA cluster (620cy/phase) serialize. The register
// ceiling (256/wave at 2 waves/SIMD; rev-4/5 spills) blocks deeper reg
// pipelining, so rev 7 shrinks the MFMA term: 32x32x16 runs at 8.07cy/32kFLOP
// vs 16x16x32's 4.85cy/16kFLOP (m119: 2495 vs 2176 TF) -> cluster 620->516cy,
// and instruction count halves (32 vs 64 MFMA/wave/K-tile). Same LDS bytes,
// same staging/swizzle/barrier skeleton. Fragment live-set SHRINKS to 48V
// peak (afE/afO/bf01/bf23, 16V each, never all live).
//
// Operand layouts (gfx950 v_mfma_f32_32x32x16_bf16):
//   A: row = lane&31, k = (lane>>5)*8 + elem   (extends our verified 16x16
//      pattern row=lane&15, k=(lane>>4)*8+elem)
//   B: col = lane&31, k = (lane>>5)*8 + elem
//   C/D: col = lane&31, row = (reg&3) + 8*(reg>>2) + 4*(lane>>5)  [m74/m101]
//
// Schedule per K-tile (phases = k-half-pair x m-pair; 2 ksteps of 16 per
// phase's MFMA cluster = 8 MFMAs):
//   p0: rd afE(m01,s01)            | stage A-h0(t+1)->b^1 | BAR | MMA m01xbf01 | BAR
//   p1: rd afO(m23,s01)+bf23(s23)  | stage A-h1(t+1)->b^1 | BAR | MMA m23xbf01 | BAR
//       (after p1's closing BAR all B(t) LDS reads are consumed -> B region free)
//   p2: rd afE(m01,s23)            | stage B-h0(t+2)->b   | BAR | MMA m01xbf23 | BAR
//   p3: rd afO(m23,s23)            | stage B-h1(t+2)->b | vmcnt(4) | BAR |
//       rd bf01'(b^1,s01) [next-tile prefetch, dead regs] | MMA m23xbf23 | BAR
// vmcnt(4) at p3: outstanding {A(t+1)x4, B(t+2)x4}; waits oldest 4 = A(t+1)
// -> tile t+1 fully resident (B(t+1) staged during t-1) before any wave's
// prefetch/next-tile reads of b^1.
//   Requires: M%256==0, N%256==0, K%128==0, (gridDim.x*gridDim.y)%8==0.
// ---------------------------------------------------------------------------

#define BAR() do { asm volatile("" ::: "memory"); \
                   __builtin_amdgcn_s_barrier(); \
                   asm volatile("" ::: "memory"); } while (0)

#define STAGE_A(buf, h, kt_) do { if ((kt_) < nt) {                            \
    const u16* g_ = Ag + (long long)(h) * hstep + ((long long)(kt_) << 6);     \
    async_load16(g_,      &lds16[(buf) * 32768 + (h) * 8192        + wave * 512]); \
    async_load16(g_ + 32, &lds16[(buf) * 32768 + (h) * 8192 + 4096 + wave * 512]); \
  } } while (0)

#define STAGE_B(buf, h, kt_) do { if ((kt_) < nt) {                            \
    const u16* g_ = Bg + (long long)(h) * hstep + ((long long)(kt_) << 6);     \
    async_load16(g_,      &lds16[16384 + (buf) * 32768 + (h) * 8192        + wave * 512]); \
    async_load16(g_ + 32, &lds16[16384 + (buf) * 32768 + (h) * 8192 + 4096 + wave * 512]); \
  } } while (0)

// A fragments: 2 m-tiles (mp*2, mp*2+1) x 2 ksteps (sp*2, sp*2+1).
// u16 offset: a_rd(+row,lh) + sp*4096(k32-half) + m32*1024 + ((s&1)^rb)*16.
#define R32A(dst, buf, mp, sp)                                                 \
    _Pragma("unroll")                                                          \
    for (int mi_ = 0; mi_ < 2; ++mi_) {                                        \
      _Pragma("unroll")                                                        \
      for (int si_ = 0; si_ < 2; ++si_)                                        \
        dst[mi_][si_] = *(const bf16x8*)&lds16[(buf) * 32768 + a_rd            \
            + (sp) * 4096 + ((mp) * 2 + mi_) * 1024 + (si_ ^ rb) * 16];        \
    }

// B fragments: 2 n-tiles x 2 ksteps of k-half sp.
#define R32B(dst, buf, sp)                                                     \
    _Pragma("unroll")                                                          \
    for (int ni_ = 0; ni_ < 2; ++ni_) {                                        \
      _Pragma("unroll")                                                        \
      for (int si_ = 0; si_ < 2; ++si_)                                        \
        dst[ni_][si_] = *(const bf16x8*)&lds16[(buf) * 32768 + b_rd            \
            + (sp) * 4096 + ni_ * 1024 + (si_ ^ rb) * 16];                     \
    }

// 8 MFMAs: acc[mp*2..mp*2+1][0..1] += af[mi][si] x bf[ni][si].
// si outermost: same-acc revisits 4 apart.
#define MMA32(mp, afv, bfv) do {                                               \
    __builtin_amdgcn_s_setprio(1);                                             \
    _Pragma("unroll")                                                          \
    for (int si_ = 0; si_ < 2; ++si_) {                                        \
      _Pragma("unroll")                                                        \
      for (int mi_ = 0; mi_ < 2; ++mi_) {                                      \
        _Pragma("unroll")                                                      \
        for (int ni_ = 0; ni_ < 2; ++ni_)                                      \
          acc[(mp) * 2 + mi_][ni_] = __builtin_amdgcn_mfma_f32_32x32x16_bf16(  \
              afv[mi_][si_], bfv[ni_][si_], acc[(mp) * 2 + mi_][ni_], 0, 0, 0);\
      }                                                                        \
    }                                                                          \
    __builtin_amdgcn_s_setprio(0);                                             \
  } while (0)

#define TILE(b, kt_) do {                                                      \
    /* p0: m01 x s01 (bf01 prefetched at prev p3) */                           \
    R32A(afE, b, 0, 0);                                                        \
    STAGE_A((b) ^ 1, 0, (kt_) + 1);                                            \
    BAR();                                                                     \
    MMA32(0, afE, bf01);                                                       \
    BAR();                                                                     \
    /* p1: m23 x s01; also read bf23 so B(t) LDS is fully consumed here */     \
    R32A(afO, b, 1, 0);                                                        \
    R32B(bf23, b, 1);                                                          \
    STAGE_A((b) ^ 1, 1, (kt_) + 1);                                            \
    BAR();                                                                     \
    MMA32(1, afO, bf01);                                                       \
    BAR();                                                                     \
    /* p2: m01 x s23; B(t) region free -> stage B(t+2) */                      \
    R32A(afE, b, 0, 1);                                                        \
    STAGE_B(b, 0, (kt_) + 2);                                                  \
    BAR();                                                                     \
    MMA32(0, afE, bf23);                                                       \
    BAR();                                                                     \
    /* p3: stage B-h1(t+2); vmcnt(4) -> t+1 resident; prefetch bf01' */        \
    R32A(afO, b, 1, 1);                                                        \
    STAGE_B(b, 1, (kt_) + 2);                                                  \
    if ((kt_) + 2 < nt) { asm volatile("s_waitcnt vmcnt(4)" ::: "memory"); }   \
    else                { asm volatile("s_waitcnt vmcnt(0)" ::: "memory"); }   \
    BAR();                                                                     \
    R32B(bf01, (b) ^ 1, 0);                                                    \
    MMA32(1, afO, bf23);                                                       \
    BAR();                                                                     \
  } while (0)

__global__ __launch_bounds__(512)
void gemm256(const u16* __restrict__ A,
             const u16* __restrict__ Bw0, const u16* __restrict__ Bw1,
             const float* __restrict__ bias0, const float* __restrict__ bias1,
             float* __restrict__ C0, float* __restrict__ C1,
             int M, int N, int K, int expls)
{
    const u16*   Bw   = blockIdx.z ? Bw1   : Bw0;
    const float* bias = blockIdx.z ? bias1 : bias0;
    float*       C    = blockIdx.z ? C1    : C0;
    const int doexp   = expls && blockIdx.z;

    __shared__ u16 lds16[65536];          // 128 KiB

    const int tid  = threadIdx.x;
    const int wave = tid >> 6;
    const int lane = tid & 63;
    const int l31  = lane & 31;           // 32x32 row/col index
    const int lh   = lane >> 5;           // k-chunk-of-8 selector
    const int rb   = (l31 >> 3) & 1;      // row-bit for chunk swizzle
    const int wm   = (wave >> 2) * 128;   // 2 wave-rows (M)
    const int wn   = (wave & 3) * 64;     // 4 wave-cols (N)

    // XCD-chunked block swizzle: same-XCD blocks get contiguous tile ranges,
    // so consecutive co-resident blocks share a 2.6MB A-panel (fits 4MB L2).
    const int nwg  = (int)(gridDim.x * gridDim.y);
    const int bid0 = (int)(blockIdx.y * gridDim.x + blockIdx.x);
    const int bid  = (bid0 & 7) * (nwg >> 3) + (bid0 >> 3);
    const int n0   = (bid % (int)gridDim.x) * 256;
    const int m0   = (bid / (int)gridDim.x) * 256;

    const int nt = K >> 6;                // # K-tiles (BK=64); even by contract

    // staging: thread t covers stage-block row (t>>2), 16B chunk (t&3), with
    // the inverse swizzle applied to the GLOBAL chunk (LDS dest is linear:
    // wave-uniform base + lane*16 by hardware). Layout per (buf, A/B, half):
    // [ks: k32-half][row 128][4 chunks of 8 u16], chunkpos = chunk ^ ((row&8)?2:0).
    const int csrc = (tid & 3) ^ ((tid >> 4) & 2);
    const u16* Ag = A  + (long long)(m0 + (tid >> 2)) * K + csrc * 8;
    const u16* Bg = Bw + (long long)(n0 + (tid >> 2)) * K + csrc * 8;
    const long long hstep = 128LL * K;

    // reader-side bases (u16 units); per-fragment adds sp*4096 + tile*1024
    // + ((s&1)^rb)*16. The row-bit XOR flips only bit1 of the chunk index,
    // so lh*8 folds into the base.
    const int a_rd = (wave >> 2) * 8192 + l31 * 32 + lh * 8;
    const int b_rd = 16384 + ((wave & 3) >> 1) * 8192
                   + ((wave & 1) * 64 + l31) * 32 + lh * 8;

    f32x16 acc[4][2] = {};                   // 128 regs (unified AGPR side)
    bf16x8 afE[2][2], afO[2][2], bf01[2][2], bf23[2][2];  // 48V peak live

    // prologue: tile0 {B-h0,B-h1,A-h0,A-h1}, tile1 {B-h0,B-h1}; wait tile0
    // (keep tile1's B halves in flight); then pre-load bf01 for tile 0.
    STAGE_B(0, 0, 0);
    STAGE_B(0, 1, 0);
    STAGE_A(0, 0, 0);
    STAGE_A(0, 1, 0);
    STAGE_B(1, 0, 1);
    STAGE_B(1, 1, 1);
    asm volatile("s_waitcnt vmcnt(4)" ::: "memory");
    BAR();
    R32B(bf01, 0, 0);

    #pragma unroll 1
    for (int kt = 0; kt < nt; kt += 2) {
        TILE(0, kt);
        TILE(1, kt + 1);
    }

    // epilogue: C/D mapping col=lane&31, row=(r&3)+8*(r>>2)+4*lh  [m74/m101]
    #pragma unroll
    for (int n32 = 0; n32 < 2; ++n32) {
        const int col = n0 + wn + n32 * 32 + l31;
        const float bv = bias[col];
        #pragma unroll
        for (int m32 = 0; m32 < 4; ++m32) {
            #pragma unroll
            for (int r = 0; r < 16; ++r) {
                const int row = m0 + wm + m32 * 32 + (r & 3) + 8 * (r >> 2) + 4 * lh;
                float v = acc[m32][n32][r] + bv;
                if (doexp) v = expf(0.5f * v);
                C[(long long)row * N + col] = v;
            }
        }
    }
}

#undef BAR
#undef STAGE_A
#undef STAGE_B
#undef R32A
#undef R32B
#undef MMA32
#undef TILE

// ---------------------------------------------------------------------------
// LayerNorm(z=1024) + tanh -> bf16. One 256-thread block per row.
// ---------------------------------------------------------------------------
__global__ __launch_bounds__(256)
void ln_tanh_kernel(const float* __restrict__ in, const float* __restrict__ g,
                    const float* __restrict__ be, u16* __restrict__ out)
{
    const int row = blockIdx.x;
    const int t = threadIdx.x;
    const float4 v = ((const float4*)(in + (long long)row * 1024))[t];
    float s  = v.x + v.y + v.z + v.w;
    float s2 = v.x * v.x + v.y * v.y + v.z * v.z + v.w * v.w;
    #pragma unroll
    for (int off = 32; off > 0; off >>= 1) {
        s  += __shfl_down(s,  off);
        s2 += __shfl_down(s2, off);
    }
    __shared__ float red[8];
    if ((t & 63) == 0) { red[t >> 6] = s; red[4 + (t >> 6)] = s2; }
    __syncthreads();
    s  = red[0] + red[1] + red[2] + red[3];
    s2 = red[4] + red[5] + red[6] + red[7];
    const float mean = s * (1.0f / 1024.0f);
    const float inv  = rsqrtf(s2 * (1.0f / 1024.0f) - mean * mean + 1e-5f);
    const float4 gg = ((const float4*)g)[t];
    const float4 bb = ((const float4*)be)[t];
    u16x4 o;
    o.x = to_bf16(tanhf((v.x - mean) * inv * gg.x + bb.x));
    o.y = to_bf16(tanhf((v.y - mean) * inv * gg.y + bb.y));
    o.z = to_bf16(tanhf((v.z - mean) * inv * gg.z + bb.z));
    o.w = to_bf16(tanhf((v.w - mean) * inv * gg.w + bb.w));
    ((u16x4*)(out + (long long)row * 1024))[t] = o;
}

// ---------------------------------------------------------------------------
// x prep: x fp32 -> x bf16 (GEMM1 A) and tanh(x) bf16 -> zc[:, 1024:5120].
// ---------------------------------------------------------------------------
__global__ __launch_bounds__(256)
void prep_x_kernel(const float* __restrict__ x, u16* __restrict__ xb,
                   u16* __restrict__ zc)
{
    const long long i = (long long)blockIdx.x * 256 + threadIdx.x;  // float4 index
    const float4 v = ((const float4*)x)[i];
    u16x4 b;
    b.x = to_bf16(v.x); b.y = to_bf16(v.y); b.z = to_bf16(v.z); b.w = to_bf16(v.w);
    ((u16x4*)xb)[i] = b;
    const long long flat = i * 4;
    const long long row = flat >> 12;        // / 4096
    const int col = (int)(flat & 4095);
    u16x4 tq;
    tq.x = to_bf16(tanhf(v.x)); tq.y = to_bf16(tanhf(v.y));
    tq.z = to_bf16(tanhf(v.z)); tq.w = to_bf16(tanhf(v.w));
    *(u16x4*)(zc + row * (long long)K_CAT + 1024 + col) = tq;
}

// ---------------------------------------------------------------------------
// Reparameterization: std was already computed by the ls-head GEMM epilogue
// (exp fused). Here: z = eps*std + mu, tanh(z) bf16 -> zc[:, 0:1024].
// ---------------------------------------------------------------------------
__global__ __launch_bounds__(256)
void reparam_kernel(const float* __restrict__ mu, const float* __restrict__ stdv,
                    const float* __restrict__ eps, u16* __restrict__ zc)
{
    const long long row = blockIdx.x;
    const int c = threadIdx.x * 4;
    const long long idx = row * 1024 + c;
    const float4 m = *(const float4*)(mu + idx);
    const float4 sd = *(const float4*)(stdv + idx);
    const float4 e = *(const float4*)(eps + idx);
    u16x4 t;
    t.x = to_bf16(tanhf(e.x * sd.x + m.x));
    t.y = to_bf16(tanhf(e.y * sd.y + m.y));
    t.z = to_bf16(tanhf(e.z * sd.z + m.z));
    t.w = to_bf16(tanhf(e.w * sd.w + m.w));
    *(u16x4*)(zc + row * (long long)K_CAT + c) = t;
}

// fp32 -> bf16 bulk convert (n4 = count of float4 quads)
__global__ __launch_bounds__(256)
void cvt_kernel(const float* __restrict__ src, u16* __restrict__ dst, long long n4)
{
    const long long i = (long long)blockIdx.x * 256 + threadIdx.x;
    if (i >= n4) return;
    const float4 v = ((const float4*)src)[i];
    u16x4 b;
    b.x = to_bf16(v.x); b.y = to_bf16(v.y); b.z = to_bf16(v.z); b.w = to_bf16(v.w);
    ((u16x4*)dst)[i] = b;
}

// Merged fp32->bf16 convert of the 4 pre-GEMM1 weight tensors (1 launch
// instead of 4). Segment boundaries in float4 quads:
//   W1: [0, 1048576) ; W2: [1048576, 1310720) ; Wmu: [1310720, 1572864) ;
//   Wls: [1572864, 1835008). Grid = 7168 blocks x 256.
__global__ __launch_bounds__(256)
void cvt4_kernel(const float* __restrict__ s0, u16* __restrict__ d0,
                 const float* __restrict__ s1, u16* __restrict__ d1,
                 const float* __restrict__ s2, u16* __restrict__ d2,
                 const float* __restrict__ s3, u16* __restrict__ d3)
{
    long long i = (long long)blockIdx.x * 256 + threadIdx.x;
    const float* s; u16* d;
    if (i < 1048576)      { s = s0; d = d0; }
    else if (i < 1310720) { s = s1; d = d1; i -= 1048576; }
    else if (i < 1572864) { s = s2; d = d2; i -= 1310720; }
    else                  { s = s3; d = d3; i -= 1572864; }
    const float4 v = ((const float4*)s)[i];
    u16x4 b;
    b.x = to_bf16(v.x); b.y = to_bf16(v.y); b.z = to_bf16(v.z); b.w = to_bf16(v.w);
    ((u16x4*)d)[i] = b;
}

extern "C" void kernel_launch(void* const* d_in, const int* in_sizes, int n_in,
                              void* d_out, int out_size, void* d_ws, size_t ws_size,
                              hipStream_t stream)
{
    const float* x   = (const float*)d_in[0];
    const float* eps = (const float*)d_in[1];
    const float* W1  = (const float*)d_in[2];
    const float* b1  = (const float*)d_in[3];
    const float* g1  = (const float*)d_in[4];
    const float* be1 = (const float*)d_in[5];
    const float* W2  = (const float*)d_in[6];
    const float* b2  = (const float*)d_in[7];
    const float* g2  = (const float*)d_in[8];
    const float* be2 = (const float*)d_in[9];
    const float* Wmu = (const float*)d_in[10];
    const float* bmu = (const float*)d_in[11];
    const float* Wls = (const float*)d_in[12];
    const float* bls = (const float*)d_in[13];
    const float* Wzw = (const float*)d_in[14];
    const float* bzw = (const float*)d_in[15];

    float* out  = (float*)d_out;                         // [8192,4096]
    float* mu   = out + (long long)M_TOT * D_OUT;        // [8192,1024]
    float* std_ = mu  + (long long)M_TOT * Z_DIM;        // [8192,1024]

    // workspace layout (bytes):
    char* ws = (char*)d_ws;
    u16*   xb   = (u16*)(ws);                  //  67,108,864  x bf16 [8192,4096]
    u16*   zc   = (u16*)(ws +  67108864);      //  83,886,080  concat bf16 [8192,5120]
    u16*   h1   = (u16*)(ws + 150994944);      //  16,777,216
    u16*   h2   = (u16*)(ws + 167772160);      //  16,777,216
    float* pre  = (float*)(ws + 184549376);    //  33,554,432  GEMM fp32 out [8192,1024]
    u16*   W1b  = (u16*)(ws + 218103808);      //   8,388,608
    u16*   W2b  = (u16*)(ws + 226492416);      //   2,097,152
    u16*   Wmub = (u16*)(ws + 228589568);      //   2,097,152
    u16*   Wlsb = (u16*)(ws + 230686720);      //   2,097,152
    u16*   Wzwb = (u16*)(ws);                  // reuses xb region after GEMM1 (42MB<=64MB)
    // total ws = 232,783,872 bytes

    // weight conversions (merged: 1 launch instead of 4)
    cvt4_kernel<<<7168, 256, 0, stream>>>(W1, W1b, W2, W2b, Wmu, Wmub, Wls, Wlsb);

    // x -> bf16 + tanh(x) into concat buffer right half
    prep_x_kernel<<<32768, 256, 0, stream>>>(x, xb, zc);

    // layer 1: pre = x @ W1^T + b1 ; h1 = tanh(LN(pre))
    gemm_bt<<<dim3(8, 64, 1), 256, 0, stream>>>(xb, W1b, W1b, b1, b1, pre, pre,
                                                M_TOT, Z_DIM, D_IN);
    ln_tanh_kernel<<<8192, 256, 0, stream>>>(pre, g1, be1, h1);

    // Wzw conversion AFTER gemm1 (Wzwb aliases xb)
    cvt_kernel<<<20480, 256, 0, stream>>>(Wzw, Wzwb, 5242880);

    // layer 2
    gemm_bt<<<dim3(8, 64, 1), 256, 0, stream>>>(h1, W2b, W2b, b2, b2, pre, pre,
                                                M_TOT, Z_DIM, Z_DIM);
    ln_tanh_kernel<<<8192, 256, 0, stream>>>(pre, g2, be2, h2);

    // mu / logsigma heads (dual GEMM via gridDim.z) — 8-phase 256^2 kernel,
    // 256 blocks = full chip. expls=1: the z=1 (ls) epilogue writes
    // std = exp(0.5*(acc+bias)) directly into the std_ output slot.
    gemm256<<<dim3(4, 32, 2), 512, 0, stream>>>(h2, Wmub, Wlsb, bmu, bls, mu, std_,
                                                M_TOT, Z_DIM, Z_DIM, 1);

    // reparameterize: tanh(eps*std + mu) -> concat left half
    reparam_kernel<<<8192, 256, 0, stream>>>(mu, std_, eps, zc);

    // final projection: out = tanh([z,x]) @ Wzw^T + bzw — the dominant GEMM
    // (343.6 GFLOP), on the 8-phase 256^2 schedule (32x32x16 MFMA).
    gemm256<<<dim3(16, 32, 1), 512, 0, stream>>>(zc, Wzwb, Wzwb, bzw, bzw, out, out,
                                                 M_TOT, D_OUT, K_CAT, 0);
}

// Round 8
// 928.716 us; speedup vs baseline: 1.0161x; 1.0161x over previous
//
#include <hip/hip_runtime.h>
#include <cstdint>

typedef unsigned short u16;
typedef __bf16 bf16x8 __attribute__((ext_vector_type(8)));
typedef float f32x4 __attribute__((ext_vector_type(4)));

#define M_TOT 8192      // B*S
#define D_IN  4096
#define Z_DIM 1024
#define D_OUT 4096
#define K_CAT 5120      // Z + D_IN

struct alignas(8) u16x4 { u16 x, y, z, w; };

__device__ __forceinline__ u16 to_bf16(float f) {
    union { float f; uint32_t u; } v; v.f = f;
    uint32_t u = v.u;
    // round-to-nearest-even
    uint32_t r = (u + 0x7FFFu + ((u >> 16) & 1u)) >> 16;
    return (u16)r;
}

__device__ __forceinline__ void async_load16(const void* g, void* l) {
    __builtin_amdgcn_global_load_lds(
        (const __attribute__((address_space(1))) void*)g,
        (__attribute__((address_space(3))) void*)l,
        16, 0, 0);
}

// ---------------------------------------------------------------------------
// GEMM (legacy 128x128 / BK=32 / 256-thread structure) — kept for the two
// N=1024 single GEMMs where a 256-tile grid would leave half the CUs idle.
// ---------------------------------------------------------------------------
__global__ __launch_bounds__(256)
void gemm_bt(const u16* __restrict__ A,
             const u16* __restrict__ Bw0, const u16* __restrict__ Bw1,
             const float* __restrict__ bias0, const float* __restrict__ bias1,
             float* __restrict__ C0, float* __restrict__ C1,
             int M, int N, int K)
{
    const u16*  Bw   = blockIdx.z ? Bw1   : Bw0;
    const float* bias = blockIdx.z ? bias1 : bias0;
    float*       C    = blockIdx.z ? C1    : C0;

    __shared__ u16 As[128 * 32];
    __shared__ u16 Bs[128 * 32];

    const int tid  = threadIdx.x;
    const int wave = tid >> 6;
    const int lane = tid & 63;
    const int m0 = blockIdx.y * 128;
    const int n0 = blockIdx.x * 128;
    const int wm = (wave & 1) * 64;
    const int wn = (wave >> 1) * 64;

    const int srow = wave * 32 + (lane >> 2);
    const int scol = (((lane & 3) ^ ((srow >> 1) & 3))) * 8;
    const long long a_off = (long long)(m0 + srow) * K + scol;
    const long long b_off = (long long)(n0 + srow) * K + scol;

    const int fr = lane & 15;   // fragment row/col
    const int fq = lane >> 4;   // quad
    const int rc = (fq ^ ((fr >> 1) & 3)) * 8;

    f32x4 acc[4][4] = {};

    for (int k0 = 0; k0 < K; k0 += 32) {
        async_load16(A  + a_off + k0,            &As[(wave * 32 +  0) * 32]);
        async_load16(A  + a_off + k0 + 16LL * K, &As[(wave * 32 + 16) * 32]);
        async_load16(Bw + b_off + k0,            &Bs[(wave * 32 +  0) * 32]);
        async_load16(Bw + b_off + k0 + 16LL * K, &Bs[(wave * 32 + 16) * 32]);
        __syncthreads();

        bf16x8 af[4], bf[4];
        #pragma unroll
        for (int i = 0; i < 4; i++)
            af[i] = *(const bf16x8*)&As[(wm + i * 16 + fr) * 32 + rc];
        #pragma unroll
        for (int i = 0; i < 4; i++)
            bf[i] = *(const bf16x8*)&Bs[(wn + i * 16 + fr) * 32 + rc];

        #pragma unroll
        for (int mi = 0; mi < 4; mi++)
            #pragma unroll
            for (int ni = 0; ni < 4; ni++)
                acc[mi][ni] = __builtin_amdgcn_mfma_f32_16x16x32_bf16(
                    af[mi], bf[ni], acc[mi][ni], 0, 0, 0);
        __syncthreads();
    }

    #pragma unroll
    for (int ni = 0; ni < 4; ni++) {
        const int col = n0 + wn + ni * 16 + fr;
        const float bv = bias[col];
        #pragma unroll
        for (int mi = 0; mi < 4; mi++) {
            const int row = m0 + wm + mi * 16 + fq * 4;
            float* cp = C + (long long)row * N + col;
            #pragma unroll
            for (int r = 0; r < 4; r++)
                cp[(long long)r * N] = acc[mi][ni][r] + bv;
        }
    }
}

// ---------------------------------------------------------------------------
// 256x256-tile 8-phase GEMM, rev 8 = rev 6 (verified 314us / MfmaUtil 47.5 /
// 0 bank conflicts — the best measured variant) + two zero-risk deltas:
//   (1) exp-fusion epilogue (expls): the ls-head writes std=exp(0.5*(acc+b))
//       directly (verified correct in rev 7), removing reparam's exp pass
//       and its 32MB write-back.
//   (2) A-h1's stage issue moves p1 -> p0. A(buf^1) was last read during
//       tile t-1 and all reads complete before t-1's closing barrier
//       (consumed-in-phase invariant), so staging both A halves at p0 is
//       race-free; p3's vmcnt(4) accounting is unchanged (outstanding =
//       A(t+1)x4 + B(t+2)x4; drains exactly A(t+1)). This widens the
//       tightest load's issue->deadline budget from ~2 phases to ~3,
//       covering an HBM-latency miss.
// Rev 7 (32x32x16 shape) regressed to 340us: its 32-lane fragment read
// pattern is a ~4-way bank conflict (3.15e7/dispatch) — reverted.
//
//   Geometry: BK=64, 512 thr = 8 waves (2M x 4N), per-wave out 128x64.
//   LDS 128 KiB: 2 dbuf x (A 32KB + B 32KB), XOR swizzle via pre-swizzled
//   GLOBAL source chunk (LDS dest linear: wave-uniform base + lane*16).
//   Staging: p0 A-h0+A-h1(t+1)->b^1, p2 B-h0(t+2)->b, p3 B-h1(t+2)->b;
//   vmcnt(4) before p3's barrier -> tile t+1 fully resident, newest 4
//   loads (B t+2) ride across the tile boundary. bf0 for tile t+1 is
//   prefetched after p3's residency barrier (dead regs, no new live range).
//   Requires: M%256==0, N%256==0, K%128==0, (gridDim.x*gridDim.y)%8==0.
// ---------------------------------------------------------------------------

#define BAR() do { asm volatile("" ::: "memory"); \
                   __builtin_amdgcn_s_barrier(); \
                   asm volatile("" ::: "memory"); } while (0)

#define STAGE_A(buf, h, kt_) do { if ((kt_) < nt) {                            \
    const u16* g_ = Ag + (long long)(h) * hstep + ((long long)(kt_) << 6);     \
    async_load16(g_,      &lds16[(buf) * 32768 + (h) * 8192        + wave * 512]); \
    async_load16(g_ + 32, &lds16[(buf) * 32768 + (h) * 8192 + 4096 + wave * 512]); \
  } } while (0)

#define STAGE_B(buf, h, kt_) do { if ((kt_) < nt) {                            \
    const u16* g_ = Bg + (long long)(h) * hstep + ((long long)(kt_) << 6);     \
    async_load16(g_,      &lds16[16384 + (buf) * 32768 + (h) * 8192        + wave * 512]); \
    async_load16(g_ + 32, &lds16[16384 + (buf) * 32768 + (h) * 8192 + 4096 + wave * 512]); \
  } } while (0)

#define LOAD_AF(buf, mbase)                                                    \
    _Pragma("unroll")                                                          \
    for (int mi_ = 0; mi_ < 4; ++mi_) {                                        \
      _Pragma("unroll")                                                        \
      for (int ks_ = 0; ks_ < 2; ++ks_)                                        \
        af[mi_][ks_] = *(const bf16x8*)&lds16[(buf) * 32768 + a_rd             \
                                              + ks_ * 4096 + ((mbase) + mi_) * 512]; \
    }

#define LOAD_B(dst, buf, nbase)                                                \
    _Pragma("unroll")                                                          \
    for (int ni_ = 0; ni_ < 2; ++ni_) {                                        \
      _Pragma("unroll")                                                        \
      for (int ks_ = 0; ks_ < 2; ++ks_)                                        \
        dst[ni_][ks_] = *(const bf16x8*)&lds16[(buf) * 32768 + b_rd            \
                                               + ks_ * 4096 + ((nbase) + ni_) * 512]; \
    }

#define MMA_Q(bfx, mo, no) do {                                                \
    __builtin_amdgcn_s_setprio(1);                                             \
    _Pragma("unroll")                                                          \
    for (int mi_ = 0; mi_ < 4; ++mi_) {                                        \
      _Pragma("unroll")                                                        \
      for (int ni_ = 0; ni_ < 2; ++ni_) {                                      \
        _Pragma("unroll")                                                      \
        for (int ks_ = 0; ks_ < 2; ++ks_)                                      \
          acc[(mo) + mi_][(no) + ni_] = __builtin_amdgcn_mfma_f32_16x16x32_bf16( \
              af[mi_][ks_], bfx[ni_][ks_], acc[(mo) + mi_][(no) + ni_], 0, 0, 0); \
      }                                                                        \
    }                                                                          \
    __builtin_amdgcn_s_setprio(0);                                             \
  } while (0)

#define TILE(b, kt_) do {                                                      \
    /* phase 0: Q0 = acc[0..3][0..1]; bf0 was prefetched in prev p3;           \
       stage BOTH A halves of t+1 (A(b^1) fully consumed during t-1) */        \
    LOAD_AF(b, 0);                                                             \
    STAGE_A((b) ^ 1, 0, (kt_) + 1);                                            \
    STAGE_A((b) ^ 1, 1, (kt_) + 1);                                            \
    BAR();                                                                     \
    MMA_Q(bf0, 0, 0);                                                          \
    BAR();                                                                     \
    /* phase 1: Q1 = acc[0..3][2..3] */                                        \
    LOAD_B(bf1, b, 2);                                                         \
    BAR();                                                                     \
    MMA_Q(bf1, 0, 2);                                                          \
    BAR();                                                                     \
    /* phase 2: Q2 = acc[4..7][0..1]; B(buf) regs consumed -> stage B(t+2) */  \
    LOAD_AF(b, 4);                                                             \
    STAGE_B(b, 0, (kt_) + 2);                                                  \
    BAR();                                                                     \
    MMA_Q(bf0, 4, 0);                                                          \
    BAR();                                                                     \
    /* phase 3: stage B-h1(t+2); vmcnt(4) -> tile t+1 resident; after the      \
       residency barrier prefetch bf0 for tile t+1 (dead regs); Q3 */          \
    STAGE_B(b, 1, (kt_) + 2);                                                  \
    if ((kt_) + 2 < nt) { asm volatile("s_waitcnt vmcnt(4)" ::: "memory"); }   \
    else                { asm volatile("s_waitcnt vmcnt(0)" ::: "memory"); }   \
    BAR();                                                                     \
    LOAD_B(bf0, (b) ^ 1, 0);                                                   \
    MMA_Q(bf1, 4, 2);                                                          \
    BAR();                                                                     \
  } while (0)

__global__ __launch_bounds__(512)
void gemm256(const u16* __restrict__ A,
             const u16* __restrict__ Bw0, const u16* __restrict__ Bw1,
             const float* __restrict__ bias0, const float* __restrict__ bias1,
             float* __restrict__ C0, float* __restrict__ C1,
             int M, int N, int K, int expls)
{
    const u16*   Bw   = blockIdx.z ? Bw1   : Bw0;
    const float* bias = blockIdx.z ? bias1 : bias0;
    float*       C    = blockIdx.z ? C1    : C0;
    const int doexp   = expls && blockIdx.z;

    __shared__ u16 lds16[65536];          // 128 KiB

    const int tid  = threadIdx.x;
    const int wave = tid >> 6;
    const int lane = tid & 63;
    const int fr   = lane & 15;
    const int fq   = lane >> 4;
    const int wm   = (wave >> 2) * 128;   // 2 wave-rows (M)
    const int wn   = (wave & 3) * 64;     // 4 wave-cols (N)

    // XCD-chunked block swizzle: same-XCD blocks get contiguous tile ranges,
    // so consecutive co-resident blocks share a 2.6MB A-panel (fits 4MB L2).
    const int nwg  = (int)(gridDim.x * gridDim.y);
    const int bid0 = (int)(blockIdx.y * gridDim.x + blockIdx.x);
    const int bid  = (bid0 & 7) * (nwg >> 3) + (bid0 >> 3);
    const int n0   = (bid % (int)gridDim.x) * 256;
    const int m0   = (bid / (int)gridDim.x) * 256;

    const int nt = K >> 6;                // # K-tiles (BK=64); even by contract

    // staging: thread t covers stage-block row (t>>2), 16B chunk (t&3), with
    // the inverse st_16x32 swizzle applied to the GLOBAL chunk (LDS dest is
    // linear: wave-uniform base + lane*16 by hardware).
    const int csrc = (tid & 3) ^ ((tid >> 4) & 2);
    const u16* Ag = A  + (long long)(m0 + (tid >> 2)) * K + csrc * 8;
    const u16* Bg = Bw + (long long)(n0 + (tid >> 2)) * K + csrc * 8;
    const long long hstep = 128LL * K;

    // reader-side swizzled LDS offsets (u16 units):
    //   off = buf*32768 + [16384 for B] + half*8192 + ks*4096
    //       + row_local*32 + ((fq*8) ^ ((row&8)<<1))
    const int swz  = (fq * 8) ^ ((fr & 8) << 1);
    const int a_rd = (wave >> 2) * 8192 + fr * 32 + swz;
    const int b_rd = 16384 + ((wave & 3) >> 1) * 8192
                   + ((wave & 1) * 64 + fr) * 32 + swz;

    f32x4 acc[8][4] = {};
    bf16x8 af[4][2], bf0[2][2], bf1[2][2];

    // prologue: tile0 {B-h0,B-h1,A-h0,A-h1}, tile1 {B-h0,B-h1}; wait tile0
    // (keep tile1's B halves in flight); then pre-load bf0 for tile 0.
    STAGE_B(0, 0, 0);
    STAGE_B(0, 1, 0);
    STAGE_A(0, 0, 0);
    STAGE_A(0, 1, 0);
    STAGE_B(1, 0, 1);
    STAGE_B(1, 1, 1);
    asm volatile("s_waitcnt vmcnt(4)" ::: "memory");
    BAR();
    LOAD_B(bf0, 0, 0);

    #pragma unroll 1
    for (int kt = 0; kt < nt; kt += 2) {
        TILE(0, kt);
        TILE(1, kt + 1);
    }

    #pragma unroll
    for (int ni = 0; ni < 4; ++ni) {
        const int col = n0 + wn + ni * 16 + fr;
        const float bv = bias[col];
        #pragma unroll
        for (int mi = 0; mi < 8; ++mi) {
            const int row = m0 + wm + mi * 16 + fq * 4;
            float* cp = C + (long long)row * N + col;
            #pragma unroll
            for (int r = 0; r < 4; ++r) {
                float v = acc[mi][ni][r] + bv;
                if (doexp) v = expf(0.5f * v);
                cp[(long long)r * N] = v;
            }
        }
    }
}

#undef BAR
#undef STAGE_A
#undef STAGE_B
#undef LOAD_AF
#undef LOAD_B
#undef MMA_Q
#undef TILE

// ---------------------------------------------------------------------------
// LayerNorm(z=1024) + tanh -> bf16. One 256-thread block per row.
// ---------------------------------------------------------------------------
__global__ __launch_bounds__(256)
void ln_tanh_kernel(const float* __restrict__ in, const float* __restrict__ g,
                    const float* __restrict__ be, u16* __restrict__ out)
{
    const int row = blockIdx.x;
    const int t = threadIdx.x;
    const float4 v = ((const float4*)(in + (long long)row * 1024))[t];
    float s  = v.x + v.y + v.z + v.w;
    float s2 = v.x * v.x + v.y * v.y + v.z * v.z + v.w * v.w;
    #pragma unroll
    for (int off = 32; off > 0; off >>= 1) {
        s  += __shfl_down(s,  off);
        s2 += __shfl_down(s2, off);
    }
    __shared__ float red[8];
    if ((t & 63) == 0) { red[t >> 6] = s; red[4 + (t >> 6)] = s2; }
    __syncthreads();
    s  = red[0] + red[1] + red[2] + red[3];
    s2 = red[4] + red[5] + red[6] + red[7];
    const float mean = s * (1.0f / 1024.0f);
    const float inv  = rsqrtf(s2 * (1.0f / 1024.0f) - mean * mean + 1e-5f);
    const float4 gg = ((const float4*)g)[t];
    const float4 bb = ((const float4*)be)[t];
    u16x4 o;
    o.x = to_bf16(tanhf((v.x - mean) * inv * gg.x + bb.x));
    o.y = to_bf16(tanhf((v.y - mean) * inv * gg.y + bb.y));
    o.z = to_bf16(tanhf((v.z - mean) * inv * gg.z + bb.z));
    o.w = to_bf16(tanhf((v.w - mean) * inv * gg.w + bb.w));
    ((u16x4*)(out + (long long)row * 1024))[t] = o;
}

// ---------------------------------------------------------------------------
// x prep: x fp32 -> x bf16 (GEMM1 A) and tanh(x) bf16 -> zc[:, 1024:5120].
// ---------------------------------------------------------------------------
__global__ __launch_bounds__(256)
void prep_x_kernel(const float* __restrict__ x, u16* __restrict__ xb,
                   u16* __restrict__ zc)
{
    const long long i = (long long)blockIdx.x * 256 + threadIdx.x;  // float4 index
    const float4 v = ((const float4*)x)[i];
    u16x4 b;
    b.x = to_bf16(v.x); b.y = to_bf16(v.y); b.z = to_bf16(v.z); b.w = to_bf16(v.w);
    ((u16x4*)xb)[i] = b;
    const long long flat = i * 4;
    const long long row = flat >> 12;        // / 4096
    const int col = (int)(flat & 4095);
    u16x4 tq;
    tq.x = to_bf16(tanhf(v.x)); tq.y = to_bf16(tanhf(v.y));
    tq.z = to_bf16(tanhf(v.z)); tq.w = to_bf16(tanhf(v.w));
    *(u16x4*)(zc + row * (long long)K_CAT + 1024 + col) = tq;
}

// ---------------------------------------------------------------------------
// Reparameterization: std was already computed by the ls-head GEMM epilogue
// (exp fused). Here: z = eps*std + mu, tanh(z) bf16 -> zc[:, 0:1024].
// ---------------------------------------------------------------------------
__global__ __launch_bounds__(256)
void reparam_kernel(const float* __restrict__ mu, const float* __restrict__ stdv,
                    const float* __restrict__ eps, u16* __restrict__ zc)
{
    const long long row = blockIdx.x;
    const int c = threadIdx.x * 4;
    const long long idx = row * 1024 + c;
    const float4 m = *(const float4*)(mu + idx);
    const float4 sd = *(const float4*)(stdv + idx);
    const float4 e = *(const float4*)(eps + idx);
    u16x4 t;
    t.x = to_bf16(tanhf(e.x * sd.x + m.x));
    t.y = to_bf16(tanhf(e.y * sd.y + m.y));
    t.z = to_bf16(tanhf(e.z * sd.z + m.z));
    t.w = to_bf16(tanhf(e.w * sd.w + m.w));
    *(u16x4*)(zc + row * (long long)K_CAT + c) = t;
}

// fp32 -> bf16 bulk convert (n4 = count of float4 quads)
__global__ __launch_bounds__(256)
void cvt_kernel(const float* __restrict__ src, u16* __restrict__ dst, long long n4)
{
    const long long i = (long long)blockIdx.x * 256 + threadIdx.x;
    if (i >= n4) return;
    const float4 v = ((const float4*)src)[i];
    u16x4 b;
    b.x = to_bf16(v.x); b.y = to_bf16(v.y); b.z = to_bf16(v.z); b.w = to_bf16(v.w);
    ((u16x4*)dst)[i] = b;
}

// Merged fp32->bf16 convert of the 4 pre-GEMM1 weight tensors (1 launch
// instead of 4). Segment boundaries in float4 quads:
//   W1: [0, 1048576) ; W2: [1048576, 1310720) ; Wmu: [1310720, 1572864) ;
//   Wls: [1572864, 1835008). Grid = 7168 blocks x 256.
__global__ __launch_bounds__(256)
void cvt4_kernel(const float* __restrict__ s0, u16* __restrict__ d0,
                 const float* __restrict__ s1, u16* __restrict__ d1,
                 const float* __restrict__ s2, u16* __restrict__ d2,
                 const float* __restrict__ s3, u16* __restrict__ d3)
{
    long long i = (long long)blockIdx.x * 256 + threadIdx.x;
    const float* s; u16* d;
    if (i < 1048576)      { s = s0; d = d0; }
    else if (i < 1310720) { s = s1; d = d1; i -= 1048576; }
    else if (i < 1572864) { s = s2; d = d2; i -= 1310720; }
    else                  { s = s3; d = d3; i -= 1572864; }
    const float4 v = ((const float4*)s)[i];
    u16x4 b;
    b.x = to_bf16(v.x); b.y = to_bf16(v.y); b.z = to_bf16(v.z); b.w = to_bf16(v.w);
    ((u16x4*)d)[i] = b;
}

extern "C" void kernel_launch(void* const* d_in, const int* in_sizes, int n_in,
                              void* d_out, int out_size, void* d_ws, size_t ws_size,
                              hipStream_t stream)
{
    const float* x   = (const float*)d_in[0];
    const float* eps = (const float*)d_in[1];
    const float* W1  = (const float*)d_in[2];
    const float* b1  = (const float*)d_in[3];
    const float* g1  = (const float*)d_in[4];
    const float* be1 = (const float*)d_in[5];
    const float* W2  = (const float*)d_in[6];
    const float* b2  = (const float*)d_in[7];
    const float* g2  = (const float*)d_in[8];
    const float* be2 = (const float*)d_in[9];
    const float* Wmu = (const float*)d_in[10];
    const float* bmu = (const float*)d_in[11];
    const float* Wls = (const float*)d_in[12];
    const float* bls = (const float*)d_in[13];
    const float* Wzw = (const float*)d_in[14];
    const float* bzw = (const float*)d_in[15];

    float* out  = (float*)d_out;                         // [8192,4096]
    float* mu   = out + (long long)M_TOT * D_OUT;        // [8192,1024]
    float* std_ = mu  + (long long)M_TOT * Z_DIM;        // [8192,1024]

    // workspace layout (bytes):
    char* ws = (char*)d_ws;
    u16*   xb   = (u16*)(ws);                  //  67,108,864  x bf16 [8192,4096]
    u16*   zc   = (u16*)(ws +  67108864);      //  83,886,080  concat bf16 [8192,5120]
    u16*   h1   = (u16*)(ws + 150994944);      //  16,777,216
    u16*   h2   = (u16*)(ws + 167772160);      //  16,777,216
    float* pre  = (float*)(ws + 184549376);    //  33,554,432  GEMM fp32 out [8192,1024]
    u16*   W1b  = (u16*)(ws + 218103808);      //   8,388,608
    u16*   W2b  = (u16*)(ws + 226492416);      //   2,097,152
    u16*   Wmub = (u16*)(ws + 228589568);      //   2,097,152
    u16*   Wlsb = (u16*)(ws + 230686720);      //   2,097,152
    u16*   Wzwb = (u16*)(ws);                  // reuses xb region after GEMM1 (42MB<=64MB)
    // total ws = 232,783,872 bytes

    // weight conversions (merged: 1 launch instead of 4)
    cvt4_kernel<<<7168, 256, 0, stream>>>(W1, W1b, W2, W2b, Wmu, Wmub, Wls, Wlsb);

    // x -> bf16 + tanh(x) into concat buffer right half
    prep_x_kernel<<<32768, 256, 0, stream>>>(x, xb, zc);

    // layer 1: pre = x @ W1^T + b1 ; h1 = tanh(LN(pre))
    gemm_bt<<<dim3(8, 64, 1), 256, 0, stream>>>(xb, W1b, W1b, b1, b1, pre, pre,
                                                M_TOT, Z_DIM, D_IN);
    ln_tanh_kernel<<<8192, 256, 0, stream>>>(pre, g1, be1, h1);

    // Wzw conversion AFTER gemm1 (Wzwb aliases xb)
    cvt_kernel<<<20480, 256, 0, stream>>>(Wzw, Wzwb, 5242880);

    // layer 2
    gemm_bt<<<dim3(8, 64, 1), 256, 0, stream>>>(h1, W2b, W2b, b2, b2, pre, pre,
                                                M_TOT, Z_DIM, Z_DIM);
    ln_tanh_kernel<<<8192, 256, 0, stream>>>(pre, g2, be2, h2);

    // mu / logsigma heads (dual GEMM via gridDim.z) — 8-phase 256^2 kernel,
    // 256 blocks = full chip. expls=1: the z=1 (ls) epilogue writes
    // std = exp(0.5*(acc+bias)) directly into the std_ output slot.
    gemm256<<<dim3(4, 32, 2), 512, 0, stream>>>(h2, Wmub, Wlsb, bmu, bls, mu, std_,
                                                M_TOT, Z_DIM, Z_DIM, 1);

    // reparameterize: tanh(eps*std + mu) -> concat left half
    reparam_kernel<<<8192, 256, 0, stream>>>(mu, std_, eps, zc);

    // final projection: out = tanh([z,x]) @ Wzw^T + bzw — the dominant GEMM
    // (343.6 GFLOP), on the 8-phase 256^2 schedule.
    gemm256<<<dim3(16, 32, 1), 512, 0, stream>>>(zc, Wzwb, Wzwb, bzw, bzw, out, out,
                                                 M_TOT, D_OUT, K_CAT, 0);
}

// Round 9
// 906.088 us; speedup vs baseline: 1.0414x; 1.0250x over previous
//
#include <hip/hip_runtime.h>
#include <cstdint>

typedef unsigned short u16;
typedef __bf16 bf16x8 __attribute__((ext_vector_type(8)));
typedef float f32x4 __attribute__((ext_vector_type(4)));

#define M_TOT 8192      // B*S
#define D_IN  4096
#define Z_DIM 1024
#define D_OUT 4096
#define K_CAT 5120      // Z + D_IN

struct alignas(8) u16x4 { u16 x, y, z, w; };

__device__ __forceinline__ u16 to_bf16(float f) {
    union { float f; uint32_t u; } v; v.f = f;
    uint32_t u = v.u;
    // round-to-nearest-even
    uint32_t r = (u + 0x7FFFu + ((u >> 16) & 1u)) >> 16;
    return (u16)r;
}

__device__ __forceinline__ void async_load16(const void* g, void* l) {
    __builtin_amdgcn_global_load_lds(
        (const __attribute__((address_space(1))) void*)g,
        (__attribute__((address_space(3))) void*)l,
        16, 0, 0);
}

// ---------------------------------------------------------------------------
// GEMM (legacy 128x128 / BK=32 / 256-thread structure) — kept for the two
// N=1024 single GEMMs where a 256-tile grid would leave half the CUs idle.
// ---------------------------------------------------------------------------
__global__ __launch_bounds__(256)
void gemm_bt(const u16* __restrict__ A,
             const u16* __restrict__ Bw0, const u16* __restrict__ Bw1,
             const float* __restrict__ bias0, const float* __restrict__ bias1,
             float* __restrict__ C0, float* __restrict__ C1,
             int M, int N, int K)
{
    const u16*  Bw   = blockIdx.z ? Bw1   : Bw0;
    const float* bias = blockIdx.z ? bias1 : bias0;
    float*       C    = blockIdx.z ? C1    : C0;

    __shared__ u16 As[128 * 32];
    __shared__ u16 Bs[128 * 32];

    const int tid  = threadIdx.x;
    const int wave = tid >> 6;
    const int lane = tid & 63;
    const int m0 = blockIdx.y * 128;
    const int n0 = blockIdx.x * 128;
    const int wm = (wave & 1) * 64;
    const int wn = (wave >> 1) * 64;

    const int srow = wave * 32 + (lane >> 2);
    const int scol = (((lane & 3) ^ ((srow >> 1) & 3))) * 8;
    const long long a_off = (long long)(m0 + srow) * K + scol;
    const long long b_off = (long long)(n0 + srow) * K + scol;

    const int fr = lane & 15;   // fragment row/col
    const int fq = lane >> 4;   // quad
    const int rc = (fq ^ ((fr >> 1) & 3)) * 8;

    f32x4 acc[4][4] = {};

    for (int k0 = 0; k0 < K; k0 += 32) {
        async_load16(A  + a_off + k0,            &As[(wave * 32 +  0) * 32]);
        async_load16(A  + a_off + k0 + 16LL * K, &As[(wave * 32 + 16) * 32]);
        async_load16(Bw + b_off + k0,            &Bs[(wave * 32 +  0) * 32]);
        async_load16(Bw + b_off + k0 + 16LL * K, &Bs[(wave * 32 + 16) * 32]);
        __syncthreads();

        bf16x8 af[4], bf[4];
        #pragma unroll
        for (int i = 0; i < 4; i++)
            af[i] = *(const bf16x8*)&As[(wm + i * 16 + fr) * 32 + rc];
        #pragma unroll
        for (int i = 0; i < 4; i++)
            bf[i] = *(const bf16x8*)&Bs[(wn + i * 16 + fr) * 32 + rc];

        #pragma unroll
        for (int mi = 0; mi < 4; mi++)
            #pragma unroll
            for (int ni = 0; ni < 4; ni++)
                acc[mi][ni] = __builtin_amdgcn_mfma_f32_16x16x32_bf16(
                    af[mi], bf[ni], acc[mi][ni], 0, 0, 0);
        __syncthreads();
    }

    #pragma unroll
    for (int ni = 0; ni < 4; ni++) {
        const int col = n0 + wn + ni * 16 + fr;
        const float bv = bias[col];
        #pragma unroll
        for (int mi = 0; mi < 4; mi++) {
            const int row = m0 + wm + mi * 16 + fq * 4;
            float* cp = C + (long long)row * N + col;
            #pragma unroll
            for (int r = 0; r < 4; r++)
                cp[(long long)r * N] = acc[mi][ni][r] + bv;
        }
    }
}

// ---------------------------------------------------------------------------
// 256x256-tile 8-phase GEMM, rev 9 = rev 6 VERBATIM (verified twice:
// 314us / MfmaUtil 47.5 / 0 bank conflicts / no spill — the best measured
// variant across 6 schedule revisions) with the exp-fusion epilogue as a
// COMPILE-TIME template parameter, so the final-projection instantiation
// carries zero epilogue branch state (rev 8's runtime `if(doexp)` + A-h1
// stage move regressed 314->329; both reverted).
//
// Cycle model (closed, rounds 1-8): per K-tile per CU, LDS fragment drain
// ~2260cy (192KB @ 85B/cy) + matrix-pipe ~2480cy (64 MFMA/SIMD @ ~19.4cy)
// serialize under the barrier-alternating phase structure -> ~4830cy
// measured. Overlap attempts: register pipelining spills (rev4/5: WRITE_SIZE
// 432/706MB — acc=128 + frags at the 256-reg/wave budget of 2 waves/SIMD),
// 32x32x16 shape bank-conflicts (rev7: 3.15e7), 2 blocks/CU impossible
// (acc=128 >= 128-reg budget at 4 waves/SIMD). This schedule is the HIP-
// source local optimum for this tile; treat as converged.
//
//   Geometry: BK=64, 512 thr = 8 waves (2M x 4N), per-wave out 128x64.
//   LDS 128 KiB: 2 dbuf x (A 32KB + B 32KB), XOR swizzle via pre-swizzled
//   GLOBAL source chunk (LDS dest linear: wave-uniform base + lane*16).
//   Staging: p0 A-h0(t+1)->b^1, p1 A-h1(t+1)->b^1, p2 B-h0(t+2)->b,
//   p3 B-h1(t+2)->b; vmcnt(4) before p3's barrier -> tile t+1 fully
//   resident, newest 4 loads (B t+2) ride across the tile boundary. bf0 for
//   tile t+1 is prefetched after p3's residency barrier (dead regs, no new
//   live range).
//   Requires: M%256==0, N%256==0, K%128==0, (gridDim.x*gridDim.y)%8==0.
// ---------------------------------------------------------------------------

#define BAR() do { asm volatile("" ::: "memory"); \
                   __builtin_amdgcn_s_barrier(); \
                   asm volatile("" ::: "memory"); } while (0)

#define STAGE_A(buf, h, kt_) do { if ((kt_) < nt) {                            \
    const u16* g_ = Ag + (long long)(h) * hstep + ((long long)(kt_) << 6);     \
    async_load16(g_,      &lds16[(buf) * 32768 + (h) * 8192        + wave * 512]); \
    async_load16(g_ + 32, &lds16[(buf) * 32768 + (h) * 8192 + 4096 + wave * 512]); \
  } } while (0)

#define STAGE_B(buf, h, kt_) do { if ((kt_) < nt) {                            \
    const u16* g_ = Bg + (long long)(h) * hstep + ((long long)(kt_) << 6);     \
    async_load16(g_,      &lds16[16384 + (buf) * 32768 + (h) * 8192        + wave * 512]); \
    async_load16(g_ + 32, &lds16[16384 + (buf) * 32768 + (h) * 8192 + 4096 + wave * 512]); \
  } } while (0)

#define LOAD_AF(buf, mbase)                                                    \
    _Pragma("unroll")                                                          \
    for (int mi_ = 0; mi_ < 4; ++mi_) {                                        \
      _Pragma("unroll")                                                        \
      for (int ks_ = 0; ks_ < 2; ++ks_)                                        \
        af[mi_][ks_] = *(const bf16x8*)&lds16[(buf) * 32768 + a_rd             \
                                              + ks_ * 4096 + ((mbase) + mi_) * 512]; \
    }

#define LOAD_B(dst, buf, nbase)                                                \
    _Pragma("unroll")                                                          \
    for (int ni_ = 0; ni_ < 2; ++ni_) {                                        \
      _Pragma("unroll")                                                        \
      for (int ks_ = 0; ks_ < 2; ++ks_)                                        \
        dst[ni_][ks_] = *(const bf16x8*)&lds16[(buf) * 32768 + b_rd            \
                                               + ks_ * 4096 + ((nbase) + ni_) * 512]; \
    }

#define MMA_Q(bfx, mo, no) do {                                                \
    __builtin_amdgcn_s_setprio(1);                                             \
    _Pragma("unroll")                                                          \
    for (int mi_ = 0; mi_ < 4; ++mi_) {                                        \
      _Pragma("unroll")                                                        \
      for (int ni_ = 0; ni_ < 2; ++ni_) {                                      \
        _Pragma("unroll")                                                      \
        for (int ks_ = 0; ks_ < 2; ++ks_)                                      \
          acc[(mo) + mi_][(no) + ni_] = __builtin_amdgcn_mfma_f32_16x16x32_bf16( \
              af[mi_][ks_], bfx[ni_][ks_], acc[(mo) + mi_][(no) + ni_], 0, 0, 0); \
      }                                                                        \
    }                                                                          \
    __builtin_amdgcn_s_setprio(0);                                             \
  } while (0)

#define TILE(b, kt_) do {                                                      \
    /* phase 0: Q0 = acc[0..3][0..1]; bf0 was prefetched in prev p3 */         \
    LOAD_AF(b, 0);                                                             \
    STAGE_A((b) ^ 1, 0, (kt_) + 1);                                            \
    BAR();                                                                     \
    MMA_Q(bf0, 0, 0);                                                          \
    BAR();                                                                     \
    /* phase 1: Q1 = acc[0..3][2..3] */                                        \
    LOAD_B(bf1, b, 2);                                                         \
    STAGE_A((b) ^ 1, 1, (kt_) + 1);                                            \
    BAR();                                                                     \
    MMA_Q(bf1, 0, 2);                                                          \
    BAR();                                                                     \
    /* phase 2: Q2 = acc[4..7][0..1]; B(buf) regs consumed -> stage B(t+2) */  \
    LOAD_AF(b, 4);                                                             \
    STAGE_B(b, 0, (kt_) + 2);                                                  \
    BAR();                                                                     \
    MMA_Q(bf0, 4, 0);                                                          \
    BAR();                                                                     \
    /* phase 3: stage B-h1(t+2); vmcnt(4) -> tile t+1 resident; after the      \
       residency barrier prefetch bf0 for tile t+1 (dead regs); Q3 */          \
    STAGE_B(b, 1, (kt_) + 2);                                                  \
    if ((kt_) + 2 < nt) { asm volatile("s_waitcnt vmcnt(4)" ::: "memory"); }   \
    else                { asm volatile("s_waitcnt vmcnt(0)" ::: "memory"); }   \
    BAR();                                                                     \
    LOAD_B(bf0, (b) ^ 1, 0);                                                   \
    MMA_Q(bf1, 4, 2);                                                          \
    BAR();                                                                     \
  } while (0)

template <bool EXPLS>
__global__ __launch_bounds__(512)
void gemm256(const u16* __restrict__ A,
             const u16* __restrict__ Bw0, const u16* __restrict__ Bw1,
             const float* __restrict__ bias0, const float* __restrict__ bias1,
             float* __restrict__ C0, float* __restrict__ C1,
             int M, int N, int K)
{
    const u16*   Bw   = blockIdx.z ? Bw1   : Bw0;
    const float* bias = blockIdx.z ? bias1 : bias0;
    float*       C    = blockIdx.z ? C1    : C0;

    __shared__ u16 lds16[65536];          // 128 KiB

    const int tid  = threadIdx.x;
    const int wave = tid >> 6;
    const int lane = tid & 63;
    const int fr   = lane & 15;
    const int fq   = lane >> 4;
    const int wm   = (wave >> 2) * 128;   // 2 wave-rows (M)
    const int wn   = (wave & 3) * 64;     // 4 wave-cols (N)

    // XCD-chunked block swizzle: same-XCD blocks get contiguous tile ranges,
    // so consecutive co-resident blocks share a 2.6MB A-panel (fits 4MB L2).
    const int nwg  = (int)(gridDim.x * gridDim.y);
    const int bid0 = (int)(blockIdx.y * gridDim.x + blockIdx.x);
    const int bid  = (bid0 & 7) * (nwg >> 3) + (bid0 >> 3);
    const int n0   = (bid % (int)gridDim.x) * 256;
    const int m0   = (bid / (int)gridDim.x) * 256;

    const int nt = K >> 6;                // # K-tiles (BK=64); even by contract

    // staging: thread t covers stage-block row (t>>2), 16B chunk (t&3), with
    // the inverse st_16x32 swizzle applied to the GLOBAL chunk (LDS dest is
    // linear: wave-uniform base + lane*16 by hardware).
    const int csrc = (tid & 3) ^ ((tid >> 4) & 2);
    const u16* Ag = A  + (long long)(m0 + (tid >> 2)) * K + csrc * 8;
    const u16* Bg = Bw + (long long)(n0 + (tid >> 2)) * K + csrc * 8;
    const long long hstep = 128LL * K;

    // reader-side swizzled LDS offsets (u16 units):
    //   off = buf*32768 + [16384 for B] + half*8192 + ks*4096
    //       + row_local*32 + ((fq*8) ^ ((row&8)<<1))
    const int swz  = (fq * 8) ^ ((fr & 8) << 1);
    const int a_rd = (wave >> 2) * 8192 + fr * 32 + swz;
    const int b_rd = 16384 + ((wave & 3) >> 1) * 8192
                   + ((wave & 1) * 64 + fr) * 32 + swz;

    f32x4 acc[8][4] = {};
    bf16x8 af[4][2], bf0[2][2], bf1[2][2];

    // prologue: tile0 {B-h0,B-h1,A-h0,A-h1}, tile1 {B-h0,B-h1}; wait tile0
    // (keep tile1's B halves in flight); then pre-load bf0 for tile 0.
    STAGE_B(0, 0, 0);
    STAGE_B(0, 1, 0);
    STAGE_A(0, 0, 0);
    STAGE_A(0, 1, 0);
    STAGE_B(1, 0, 1);
    STAGE_B(1, 1, 1);
    asm volatile("s_waitcnt vmcnt(4)" ::: "memory");
    BAR();
    LOAD_B(bf0, 0, 0);

    #pragma unroll 1
    for (int kt = 0; kt < nt; kt += 2) {
        TILE(0, kt);
        TILE(1, kt + 1);
    }

    #pragma unroll
    for (int ni = 0; ni < 4; ++ni) {
        const int col = n0 + wn + ni * 16 + fr;
        const float bv = bias[col];
        #pragma unroll
        for (int mi = 0; mi < 8; ++mi) {
            const int row = m0 + wm + mi * 16 + fq * 4;
            float* cp = C + (long long)row * N + col;
            #pragma unroll
            for (int r = 0; r < 4; ++r) {
                float v = acc[mi][ni][r] + bv;
                if constexpr (EXPLS) { if (blockIdx.z) v = expf(0.5f * v); }
                cp[(long long)r * N] = v;
            }
        }
    }
}

#undef BAR
#undef STAGE_A
#undef STAGE_B
#undef LOAD_AF
#undef LOAD_B
#undef MMA_Q
#undef TILE

// ---------------------------------------------------------------------------
// LayerNorm(z=1024) + tanh -> bf16. One 256-thread block per row.
// ---------------------------------------------------------------------------
__global__ __launch_bounds__(256)
void ln_tanh_kernel(const float* __restrict__ in, const float* __restrict__ g,
                    const float* __restrict__ be, u16* __restrict__ out)
{
    const int row = blockIdx.x;
    const int t = threadIdx.x;
    const float4 v = ((const float4*)(in + (long long)row * 1024))[t];
    float s  = v.x + v.y + v.z + v.w;
    float s2 = v.x * v.x + v.y * v.y + v.z * v.z + v.w * v.w;
    #pragma unroll
    for (int off = 32; off > 0; off >>= 1) {
        s  += __shfl_down(s,  off);
        s2 += __shfl_down(s2, off);
    }
    __shared__ float red[8];
    if ((t & 63) == 0) { red[t >> 6] = s; red[4 + (t >> 6)] = s2; }
    __syncthreads();
    s  = red[0] + red[1] + red[2] + red[3];
    s2 = red[4] + red[5] + red[6] + red[7];
    const float mean = s * (1.0f / 1024.0f);
    const float inv  = rsqrtf(s2 * (1.0f / 1024.0f) - mean * mean + 1e-5f);
    const float4 gg = ((const float4*)g)[t];
    const float4 bb = ((const float4*)be)[t];
    u16x4 o;
    o.x = to_bf16(tanhf((v.x - mean) * inv * gg.x + bb.x));
    o.y = to_bf16(tanhf((v.y - mean) * inv * gg.y + bb.y));
    o.z = to_bf16(tanhf((v.z - mean) * inv * gg.z + bb.z));
    o.w = to_bf16(tanhf((v.w - mean) * inv * gg.w + bb.w));
    ((u16x4*)(out + (long long)row * 1024))[t] = o;
}

// ---------------------------------------------------------------------------
// x prep: x fp32 -> x bf16 (GEMM1 A) and tanh(x) bf16 -> zc[:, 1024:5120].
// ---------------------------------------------------------------------------
__global__ __launch_bounds__(256)
void prep_x_kernel(const float* __restrict__ x, u16* __restrict__ xb,
                   u16* __restrict__ zc)
{
    const long long i = (long long)blockIdx.x * 256 + threadIdx.x;  // float4 index
    const float4 v = ((const float4*)x)[i];
    u16x4 b;
    b.x = to_bf16(v.x); b.y = to_bf16(v.y); b.z = to_bf16(v.z); b.w = to_bf16(v.w);
    ((u16x4*)xb)[i] = b;
    const long long flat = i * 4;
    const long long row = flat >> 12;        // / 4096
    const int col = (int)(flat & 4095);
    u16x4 tq;
    tq.x = to_bf16(tanhf(v.x)); tq.y = to_bf16(tanhf(v.y));
    tq.z = to_bf16(tanhf(v.z)); tq.w = to_bf16(tanhf(v.w));
    *(u16x4*)(zc + row * (long long)K_CAT + 1024 + col) = tq;
}

// ---------------------------------------------------------------------------
// Reparameterization: std was already computed by the ls-head GEMM epilogue
// (exp fused). Here: z = eps*std + mu, tanh(z) bf16 -> zc[:, 0:1024].
// ---------------------------------------------------------------------------
__global__ __launch_bounds__(256)
void reparam_kernel(const float* __restrict__ mu, const float* __restrict__ stdv,
                    const float* __restrict__ eps, u16* __restrict__ zc)
{
    const long long row = blockIdx.x;
    const int c = threadIdx.x * 4;
    const long long idx = row * 1024 + c;
    const float4 m = *(const float4*)(mu + idx);
    const float4 sd = *(const float4*)(stdv + idx);
    const float4 e = *(const float4*)(eps + idx);
    u16x4 t;
    t.x = to_bf16(tanhf(e.x * sd.x + m.x));
    t.y = to_bf16(tanhf(e.y * sd.y + m.y));
    t.z = to_bf16(tanhf(e.z * sd.z + m.z));
    t.w = to_bf16(tanhf(e.w * sd.w + m.w));
    *(u16x4*)(zc + row * (long long)K_CAT + c) = t;
}

// fp32 -> bf16 bulk convert (n4 = count of float4 quads)
__global__ __launch_bounds__(256)
void cvt_kernel(const float* __restrict__ src, u16* __restrict__ dst, long long n4)
{
    const long long i = (long long)blockIdx.x * 256 + threadIdx.x;
    if (i >= n4) return;
    const float4 v = ((const float4*)src)[i];
    u16x4 b;
    b.x = to_bf16(v.x); b.y = to_bf16(v.y); b.z = to_bf16(v.z); b.w = to_bf16(v.w);
    ((u16x4*)dst)[i] = b;
}

// Merged fp32->bf16 convert of the 4 pre-GEMM1 weight tensors (1 launch
// instead of 4). Segment boundaries in float4 quads:
//   W1: [0, 1048576) ; W2: [1048576, 1310720) ; Wmu: [1310720, 1572864) ;
//   Wls: [1572864, 1835008). Grid = 7168 blocks x 256.
__global__ __launch_bounds__(256)
void cvt4_kernel(const float* __restrict__ s0, u16* __restrict__ d0,
                 const float* __restrict__ s1, u16* __restrict__ d1,
                 const float* __restrict__ s2, u16* __restrict__ d2,
                 const float* __restrict__ s3, u16* __restrict__ d3)
{
    long long i = (long long)blockIdx.x * 256 + threadIdx.x;
    const float* s; u16* d;
    if (i < 1048576)      { s = s0; d = d0; }
    else if (i < 1310720) { s = s1; d = d1; i -= 1048576; }
    else if (i < 1572864) { s = s2; d = d2; i -= 1310720; }
    else                  { s = s3; d = d3; i -= 1572864; }
    const float4 v = ((const float4*)s)[i];
    u16x4 b;
    b.x = to_bf16(v.x); b.y = to_bf16(v.y); b.z = to_bf16(v.z); b.w = to_bf16(v.w);
    ((u16x4*)d)[i] = b;
}

extern "C" void kernel_launch(void* const* d_in, const int* in_sizes, int n_in,
                              void* d_out, int out_size, void* d_ws, size_t ws_size,
                              hipStream_t stream)
{
    const float* x   = (const float*)d_in[0];
    const float* eps = (const float*)d_in[1];
    const float* W1  = (const float*)d_in[2];
    const float* b1  = (const float*)d_in[3];
    const float* g1  = (const float*)d_in[4];
    const float* be1 = (const float*)d_in[5];
    const float* W2  = (const float*)d_in[6];
    const float* b2  = (const float*)d_in[7];
    const float* g2  = (const float*)d_in[8];
    const float* be2 = (const float*)d_in[9];
    const float* Wmu = (const float*)d_in[10];
    const float* bmu = (const float*)d_in[11];
    const float* Wls = (const float*)d_in[12];
    const float* bls = (const float*)d_in[13];
    const float* Wzw = (const float*)d_in[14];
    const float* bzw = (const float*)d_in[15];

    float* out  = (float*)d_out;                         // [8192,4096]
    float* mu   = out + (long long)M_TOT * D_OUT;        // [8192,1024]
    float* std_ = mu  + (long long)M_TOT * Z_DIM;        // [8192,1024]

    // workspace layout (bytes):
    char* ws = (char*)d_ws;
    u16*   xb   = (u16*)(ws);                  //  67,108,864  x bf16 [8192,4096]
    u16*   zc   = (u16*)(ws +  67108864);      //  83,886,080  concat bf16 [8192,5120]
    u16*   h1   = (u16*)(ws + 150994944);      //  16,777,216
    u16*   h2   = (u16*)(ws + 167772160);      //  16,777,216
    float* pre  = (float*)(ws + 184549376);    //  33,554,432  GEMM fp32 out [8192,1024]
    u16*   W1b  = (u16*)(ws + 218103808);      //   8,388,608
    u16*   W2b  = (u16*)(ws + 226492416);      //   2,097,152
    u16*   Wmub = (u16*)(ws + 228589568);      //   2,097,152
    u16*   Wlsb = (u16*)(ws + 230686720);      //   2,097,152
    u16*   Wzwb = (u16*)(ws);                  // reuses xb region after GEMM1 (42MB<=64MB)
    // total ws = 232,783,872 bytes

    // weight conversions (merged: 1 launch instead of 4)
    cvt4_kernel<<<7168, 256, 0, stream>>>(W1, W1b, W2, W2b, Wmu, Wmub, Wls, Wlsb);

    // x -> bf16 + tanh(x) into concat buffer right half
    prep_x_kernel<<<32768, 256, 0, stream>>>(x, xb, zc);

    // layer 1: pre = x @ W1^T + b1 ; h1 = tanh(LN(pre))
    gemm_bt<<<dim3(8, 64, 1), 256, 0, stream>>>(xb, W1b, W1b, b1, b1, pre, pre,
                                                M_TOT, Z_DIM, D_IN);
    ln_tanh_kernel<<<8192, 256, 0, stream>>>(pre, g1, be1, h1);

    // Wzw conversion AFTER gemm1 (Wzwb aliases xb)
    cvt_kernel<<<20480, 256, 0, stream>>>(Wzw, Wzwb, 5242880);

    // layer 2
    gemm_bt<<<dim3(8, 64, 1), 256, 0, stream>>>(h1, W2b, W2b, b2, b2, pre, pre,
                                                M_TOT, Z_DIM, Z_DIM);
    ln_tanh_kernel<<<8192, 256, 0, stream>>>(pre, g2, be2, h2);

    // mu / logsigma heads (dual GEMM via gridDim.z) — 8-phase 256^2 kernel,
    // 256 blocks = full chip. EXPLS=true: the z=1 (ls) epilogue writes
    // std = exp(0.5*(acc+bias)) directly into the std_ output slot.
    gemm256<true><<<dim3(4, 32, 2), 512, 0, stream>>>(h2, Wmub, Wlsb, bmu, bls,
                                                      mu, std_,
                                                      M_TOT, Z_DIM, Z_DIM);

    // reparameterize: tanh(eps*std + mu) -> concat left half
    reparam_kernel<<<8192, 256, 0, stream>>>(mu, std_, eps, zc);

    // final projection: out = tanh([z,x]) @ Wzw^T + bzw — the dominant GEMM
    // (343.6 GFLOP), on the 8-phase 256^2 schedule (rev-6 verified best).
    gemm256<false><<<dim3(16, 32, 1), 512, 0, stream>>>(zc, Wzwb, Wzwb, bzw, bzw,
                                                        out, out,
                                                        M_TOT, D_OUT, K_CAT);
}

// Round 10
// 877.166 us; speedup vs baseline: 1.0758x; 1.0330x over previous
//
#include <hip/hip_runtime.h>
#include <cstdint>

typedef unsigned short u16;
typedef __bf16 bf16x8 __attribute__((ext_vector_type(8)));
typedef float f32x4 __attribute__((ext_vector_type(4)));

#define M_TOT 8192      // B*S
#define D_IN  4096
#define Z_DIM 1024
#define D_OUT 4096
#define K_CAT 5120      // Z + D_IN

struct alignas(8) u16x4 { u16 x, y, z, w; };

__device__ __forceinline__ u16 to_bf16(float f) {
    union { float f; uint32_t u; } v; v.f = f;
    uint32_t u = v.u;
    // round-to-nearest-even
    uint32_t r = (u + 0x7FFFu + ((u >> 16) & 1u)) >> 16;
    return (u16)r;
}

__device__ __forceinline__ void async_load16(const void* g, void* l) {
    __builtin_amdgcn_global_load_lds(
        (const __attribute__((address_space(1))) void*)g,
        (__attribute__((address_space(3))) void*)l,
        16, 0, 0);
}

#define BAR() do { asm volatile("" ::: "memory"); \
                   __builtin_amdgcn_s_barrier(); \
                   asm volatile("" ::: "memory"); } while (0)

// ---------------------------------------------------------------------------
// 256x256-tile 8-phase GEMM — rev-6 schedule, verified best (317us/48.5%/
// 0 conflicts on the final projection). Converged; do not perturb.
//   Geometry: BK=64, 512 thr = 8 waves (2M x 4N), per-wave out 128x64.
//   LDS 128 KiB: 2 dbuf x (A 32KB + B 32KB), XOR swizzle via pre-swizzled
//   GLOBAL source chunk (LDS dest linear: wave-uniform base + lane*16).
//   Staging: p0 A-h0(t+1)->b^1, p1 A-h1(t+1)->b^1, p2 B-h0(t+2)->b,
//   p3 B-h1(t+2)->b; vmcnt(4) before p3's barrier -> tile t+1 fully
//   resident; bf0(t+1) prefetched after the residency barrier (dead regs).
//   Requires: M%256==0, N%256==0, K%128==0, (gridDim.x*gridDim.y)%8==0.
// ---------------------------------------------------------------------------

#define STAGE_A(buf, h, kt_) do { if ((kt_) < nt) {                            \
    const u16* g_ = Ag + (long long)(h) * hstep + ((long long)(kt_) << 6);     \
    async_load16(g_,      &lds16[(buf) * 32768 + (h) * 8192        + wave * 512]); \
    async_load16(g_ + 32, &lds16[(buf) * 32768 + (h) * 8192 + 4096 + wave * 512]); \
  } } while (0)

#define STAGE_B(buf, h, kt_) do { if ((kt_) < nt) {                            \
    const u16* g_ = Bg + (long long)(h) * hstep + ((long long)(kt_) << 6);     \
    async_load16(g_,      &lds16[16384 + (buf) * 32768 + (h) * 8192        + wave * 512]); \
    async_load16(g_ + 32, &lds16[16384 + (buf) * 32768 + (h) * 8192 + 4096 + wave * 512]); \
  } } while (0)

#define LOAD_AF(buf, mbase)                                                    \
    _Pragma("unroll")                                                          \
    for (int mi_ = 0; mi_ < 4; ++mi_) {                                        \
      _Pragma("unroll")                                                        \
      for (int ks_ = 0; ks_ < 2; ++ks_)                                        \
        af[mi_][ks_] = *(const bf16x8*)&lds16[(buf) * 32768 + a_rd             \
                                              + ks_ * 4096 + ((mbase) + mi_) * 512]; \
    }

#define LOAD_B(dst, buf, nbase)                                                \
    _Pragma("unroll")                                                          \
    for (int ni_ = 0; ni_ < 2; ++ni_) {                                        \
      _Pragma("unroll")                                                        \
      for (int ks_ = 0; ks_ < 2; ++ks_)                                        \
        dst[ni_][ks_] = *(const bf16x8*)&lds16[(buf) * 32768 + b_rd            \
                                               + ks_ * 4096 + ((nbase) + ni_) * 512]; \
    }

#define MMA_Q(bfx, mo, no) do {                                                \
    __builtin_amdgcn_s_setprio(1);                                             \
    _Pragma("unroll")                                                          \
    for (int mi_ = 0; mi_ < 4; ++mi_) {                                        \
      _Pragma("unroll")                                                        \
      for (int ni_ = 0; ni_ < 2; ++ni_) {                                      \
        _Pragma("unroll")                                                      \
        for (int ks_ = 0; ks_ < 2; ++ks_)                                      \
          acc[(mo) + mi_][(no) + ni_] = __builtin_amdgcn_mfma_f32_16x16x32_bf16( \
              af[mi_][ks_], bfx[ni_][ks_], acc[(mo) + mi_][(no) + ni_], 0, 0, 0); \
      }                                                                        \
    }                                                                          \
    __builtin_amdgcn_s_setprio(0);                                             \
  } while (0)

#define TILE(b, kt_) do {                                                      \
    LOAD_AF(b, 0);                                                             \
    STAGE_A((b) ^ 1, 0, (kt_) + 1);                                            \
    BAR();                                                                     \
    MMA_Q(bf0, 0, 0);                                                          \
    BAR();                                                                     \
    LOAD_B(bf1, b, 2);                                                         \
    STAGE_A((b) ^ 1, 1, (kt_) + 1);                                            \
    BAR();                                                                     \
    MMA_Q(bf1, 0, 2);                                                          \
    BAR();                                                                     \
    LOAD_AF(b, 4);                                                             \
    STAGE_B(b, 0, (kt_) + 2);                                                  \
    BAR();                                                                     \
    MMA_Q(bf0, 4, 0);                                                          \
    BAR();                                                                     \
    STAGE_B(b, 1, (kt_) + 2);                                                  \
    if ((kt_) + 2 < nt) { asm volatile("s_waitcnt vmcnt(4)" ::: "memory"); }   \
    else                { asm volatile("s_waitcnt vmcnt(0)" ::: "memory"); }   \
    BAR();                                                                     \
    LOAD_B(bf0, (b) ^ 1, 0);                                                   \
    MMA_Q(bf1, 4, 2);                                                          \
    BAR();                                                                     \
  } while (0)

template <bool EXPLS>
__global__ __launch_bounds__(512)
void gemm256(const u16* __restrict__ A,
             const u16* __restrict__ Bw0, const u16* __restrict__ Bw1,
             const float* __restrict__ bias0, const float* __restrict__ bias1,
             float* __restrict__ C0, float* __restrict__ C1,
             int M, int N, int K)
{
    const u16*   Bw   = blockIdx.z ? Bw1   : Bw0;
    const float* bias = blockIdx.z ? bias1 : bias0;
    float*       C    = blockIdx.z ? C1    : C0;

    __shared__ u16 lds16[65536];          // 128 KiB

    const int tid  = threadIdx.x;
    const int wave = tid >> 6;
    const int lane = tid & 63;
    const int fr   = lane & 15;
    const int fq   = lane >> 4;
    const int wm   = (wave >> 2) * 128;   // 2 wave-rows (M)
    const int wn   = (wave & 3) * 64;     // 4 wave-cols (N)

    const int nwg  = (int)(gridDim.x * gridDim.y);
    const int bid0 = (int)(blockIdx.y * gridDim.x + blockIdx.x);
    const int bid  = (bid0 & 7) * (nwg >> 3) + (bid0 >> 3);
    const int n0   = (bid % (int)gridDim.x) * 256;
    const int m0   = (bid / (int)gridDim.x) * 256;

    const int nt = K >> 6;                // # K-tiles (BK=64); even by contract

    const int csrc = (tid & 3) ^ ((tid >> 4) & 2);
    const u16* Ag = A  + (long long)(m0 + (tid >> 2)) * K + csrc * 8;
    const u16* Bg = Bw + (long long)(n0 + (tid >> 2)) * K + csrc * 8;
    const long long hstep = 128LL * K;

    const int swz  = (fq * 8) ^ ((fr & 8) << 1);
    const int a_rd = (wave >> 2) * 8192 + fr * 32 + swz;
    const int b_rd = 16384 + ((wave & 3) >> 1) * 8192
                   + ((wave & 1) * 64 + fr) * 32 + swz;

    f32x4 acc[8][4] = {};
    bf16x8 af[4][2], bf0[2][2], bf1[2][2];

    STAGE_B(0, 0, 0);
    STAGE_B(0, 1, 0);
    STAGE_A(0, 0, 0);
    STAGE_A(0, 1, 0);
    STAGE_B(1, 0, 1);
    STAGE_B(1, 1, 1);
    asm volatile("s_waitcnt vmcnt(4)" ::: "memory");
    BAR();
    LOAD_B(bf0, 0, 0);

    #pragma unroll 1
    for (int kt = 0; kt < nt; kt += 2) {
        TILE(0, kt);
        TILE(1, kt + 1);
    }

    #pragma unroll
    for (int ni = 0; ni < 4; ++ni) {
        const int col = n0 + wn + ni * 16 + fr;
        const float bv = bias[col];
        #pragma unroll
        for (int mi = 0; mi < 8; ++mi) {
            const int row = m0 + wm + mi * 16 + fq * 4;
            float* cp = C + (long long)row * N + col;
            #pragma unroll
            for (int r = 0; r < 4; ++r) {
                float v = acc[mi][ni][r] + bv;
                if constexpr (EXPLS) { if (blockIdx.z) v = expf(0.5f * v); }
                cp[(long long)r * N] = v;
            }
        }
    }
}

#undef STAGE_A
#undef STAGE_B
#undef LOAD_AF
#undef LOAD_B
#undef MMA_Q
#undef TILE

// ---------------------------------------------------------------------------
// 256x128-tile GEMM (gemm128n) — the rev-6 schedule adapted for N=1024 layer
// GEMMs (replaces the 128^2/BK=32 gemm_bt, the last m97-class structure).
//   Geometry: BM=256, BN=128, BK=64, 512 thr = 8 waves (2M x 4N), per-wave
//   out 128x32. Grid (N/128, M/256) = 256 blocks = exactly 1 block/CU.
//   LDS 96 KiB: 2 dbuf x (A 32KB [2 halves] + B 16KB). Same XOR swizzle via
//   pre-swizzled global source chunk; LDS dest linear.
//   Schedule per K-tile (2 phases; bf register sets alternate by tile parity
//   so the t+1 prefetch never WARs the in-flight MFMAs):
//     p0: rd af-lo (8) | stage A-h0(t+1)->b^1 | BAR | 16 MFMA (m-lo) | BAR
//     p1: rd af-hi (8) | stage A-h1(t+1)->b^1 + B(t+2)->b |
//         vmcnt(2) [t+1 resident; only B(t+2) rides] | BAR |
//         rd bfNxt(t+1) from b^1 (4, dead regs) | 16 MFMA (m-hi) | BAR
//   Safety (rev-6 invariants): stages into A(b^1) target a region whose
//   reads completed before tile t-1's closing barrier; stage B(t+2)->b is
//   >=2 barriers after the last bf(t) read (t-1 p1); vmcnt(2) drains
//   B(t+1)+A(t+1) exactly (8 outstanding, newest 2 = B(t+2)); tail tiles
//   use vmcnt(0). Registers: acc 64 + af 32 + bfA/bfB 32 ~ 190 < 256.
//   Requires: M%256==0, N%128==0, K%128==0, (gridDim.x*gridDim.y)%8==0.
// ---------------------------------------------------------------------------

#define STAGE_A1(buf, h, kt_) do { if ((kt_) < nt) {                           \
    const u16* g_ = Ag + (long long)(h) * hstep + ((long long)(kt_) << 6);     \
    async_load16(g_,      &lds16[(buf) * 24576 + (h) * 8192        + wave * 512]); \
    async_load16(g_ + 32, &lds16[(buf) * 24576 + (h) * 8192 + 4096 + wave * 512]); \
  } } while (0)

#define STAGE_B1(buf, kt_) do { if ((kt_) < nt) {                              \
    const u16* g_ = Bg + ((long long)(kt_) << 6);                              \
    async_load16(g_,      &lds16[(buf) * 24576 + 16384        + wave * 512]);  \
    async_load16(g_ + 32, &lds16[(buf) * 24576 + 16384 + 4096 + wave * 512]);  \
  } } while (0)

#define LOAD_AF1(buf, mbase)                                                   \
    _Pragma("unroll")                                                          \
    for (int mi_ = 0; mi_ < 4; ++mi_) {                                        \
      _Pragma("unroll")                                                        \
      for (int ks_ = 0; ks_ < 2; ++ks_)                                        \
        af[mi_][ks_] = *(const bf16x8*)&lds16[(buf) * 24576 + a_rd             \
                                              + ks_ * 4096 + ((mbase) + mi_) * 512]; \
    }

#define LOAD_BF1(dst, buf)                                                     \
    _Pragma("unroll")                                                          \
    for (int ni_ = 0; ni_ < 2; ++ni_) {                                        \
      _Pragma("unroll")                                                        \
      for (int ks_ = 0; ks_ < 2; ++ks_)                                        \
        dst[ni_][ks_] = *(const bf16x8*)&lds16[(buf) * 24576 + b_rd            \
                                               + ks_ * 4096 + ni_ * 512];      \
    }

#define MMA_H(bfx, mo) do {                                                    \
    __builtin_amdgcn_s_setprio(1);                                             \
    _Pragma("unroll")                                                          \
    for (int mi_ = 0; mi_ < 4; ++mi_) {                                        \
      _Pragma("unroll")                                                        \
      for (int ni_ = 0; ni_ < 2; ++ni_) {                                      \
        _Pragma("unroll")                                                      \
        for (int ks_ = 0; ks_ < 2; ++ks_)                                      \
          acc[(mo) + mi_][ni_] = __builtin_amdgcn_mfma_f32_16x16x32_bf16(      \
              af[mi_][ks_], bfx[ni_][ks_], acc[(mo) + mi_][ni_], 0, 0, 0);     \
      }                                                                        \
    }                                                                          \
    __builtin_amdgcn_s_setprio(0);                                             \
  } while (0)

#define TILE1(b, kt_, bfCur, bfNxt) do {                                       \
    /* p0: af-lo; stage A-h0(t+1); MMA m-lo */                                 \
    LOAD_AF1(b, 0);                                                            \
    STAGE_A1((b) ^ 1, 0, (kt_) + 1);                                           \
    BAR();                                                                     \
    MMA_H(bfCur, 0);                                                           \
    BAR();                                                                     \
    /* p1: af-hi; stage A-h1(t+1) + B(t+2); residency; prefetch bf(t+1) */     \
    LOAD_AF1(b, 4);                                                            \
    STAGE_A1((b) ^ 1, 1, (kt_) + 1);                                           \
    STAGE_B1(b, (kt_) + 2);                                                    \
    if ((kt_) + 2 < nt) { asm volatile("s_waitcnt vmcnt(2)" ::: "memory"); }   \
    else                { asm volatile("s_waitcnt vmcnt(0)" ::: "memory"); }   \
    BAR();                                                                     \
    LOAD_BF1(bfNxt, (b) ^ 1);                                                  \
    MMA_H(bfCur, 4);                                                           \
    BAR();                                                                     \
  } while (0)

__global__ __launch_bounds__(512)
void gemm128n(const u16* __restrict__ A, const u16* __restrict__ Bw,
              const float* __restrict__ bias, float* __restrict__ C,
              int M, int N, int K)
{
    __shared__ u16 lds16[49152];          // 96 KiB

    const int tid  = threadIdx.x;
    const int wave = tid >> 6;
    const int lane = tid & 63;
    const int fr   = lane & 15;
    const int fq   = lane >> 4;
    const int wm   = (wave >> 2) * 128;   // 2 wave-rows (M)
    const int wn   = (wave & 3) * 32;     // 4 wave-cols (N)

    const int nwg  = (int)(gridDim.x * gridDim.y);
    const int bid0 = (int)(blockIdx.y * gridDim.x + blockIdx.x);
    const int bid  = (bid0 & 7) * (nwg >> 3) + (bid0 >> 3);
    const int n0   = (bid % (int)gridDim.x) * 128;
    const int m0   = (bid / (int)gridDim.x) * 256;

    const int nt = K >> 6;                // even by contract (K%128==0)

    const int csrc = (tid & 3) ^ ((tid >> 4) & 2);
    const u16* Ag = A  + (long long)(m0 + (tid >> 2)) * K + csrc * 8;
    const u16* Bg = Bw + (long long)(n0 + (tid >> 2)) * K + csrc * 8;
    const long long hstep = 128LL * K;

    const int swz  = (fq * 8) ^ ((fr & 8) << 1);
    const int a_rd = (wave >> 2) * 8192 + fr * 32 + swz;
    const int b_rd = 16384 + ((wave & 3) * 32 + fr) * 32 + swz;

    f32x4 acc[8][2] = {};
    bf16x8 af[4][2], bfA[2][2], bfB[2][2];

    // prologue: B(0), A(0) both halves, B(1); drain tile0 (keep B(1)).
    STAGE_B1(0, 0);
    STAGE_A1(0, 0, 0);
    STAGE_A1(0, 1, 0);
    STAGE_B1(1, 1);
    asm volatile("s_waitcnt vmcnt(2)" ::: "memory");
    BAR();
    LOAD_BF1(bfA, 0);

    #pragma unroll 1
    for (int kt = 0; kt < nt; kt += 2) {
        TILE1(0, kt,     bfA, bfB);
        TILE1(1, kt + 1, bfB, bfA);
    }

    #pragma unroll
    for (int ni = 0; ni < 2; ++ni) {
        const int col = n0 + wn + ni * 16 + fr;
        const float bv = bias[col];
        #pragma unroll
        for (int mi = 0; mi < 8; ++mi) {
            const int row = m0 + wm + mi * 16 + fq * 4;
            float* cp = C + (long long)row * N + col;
            #pragma unroll
            for (int r = 0; r < 4; ++r)
                cp[(long long)r * N] = acc[mi][ni][r] + bv;
        }
    }
}

#undef STAGE_A1
#undef STAGE_B1
#undef LOAD_AF1
#undef LOAD_BF1
#undef MMA_H
#undef TILE1

// ---------------------------------------------------------------------------
// LayerNorm(z=1024) + tanh -> bf16. One 256-thread block per row.
// ---------------------------------------------------------------------------
__global__ __launch_bounds__(256)
void ln_tanh_kernel(const float* __restrict__ in, const float* __restrict__ g,
                    const float* __restrict__ be, u16* __restrict__ out)
{
    const int row = blockIdx.x;
    const int t = threadIdx.x;
    const float4 v = ((const float4*)(in + (long long)row * 1024))[t];
    float s  = v.x + v.y + v.z + v.w;
    float s2 = v.x * v.x + v.y * v.y + v.z * v.z + v.w * v.w;
    #pragma unroll
    for (int off = 32; off > 0; off >>= 1) {
        s  += __shfl_down(s,  off);
        s2 += __shfl_down(s2, off);
    }
    __shared__ float red[8];
    if ((t & 63) == 0) { red[t >> 6] = s; red[4 + (t >> 6)] = s2; }
    __syncthreads();
    s  = red[0] + red[1] + red[2] + red[3];
    s2 = red[4] + red[5] + red[6] + red[7];
    const float mean = s * (1.0f / 1024.0f);
    const float inv  = rsqrtf(s2 * (1.0f / 1024.0f) - mean * mean + 1e-5f);
    const float4 gg = ((const float4*)g)[t];
    const float4 bb = ((const float4*)be)[t];
    u16x4 o;
    o.x = to_bf16(tanhf((v.x - mean) * inv * gg.x + bb.x));
    o.y = to_bf16(tanhf((v.y - mean) * inv * gg.y + bb.y));
    o.z = to_bf16(tanhf((v.z - mean) * inv * gg.z + bb.z));
    o.w = to_bf16(tanhf((v.w - mean) * inv * gg.w + bb.w));
    ((u16x4*)(out + (long long)row * 1024))[t] = o;
}

// ---------------------------------------------------------------------------
// x prep: x fp32 -> x bf16 (GEMM1 A) and tanh(x) bf16 -> zc[:, 1024:5120].
// ---------------------------------------------------------------------------
__global__ __launch_bounds__(256)
void prep_x_kernel(const float* __restrict__ x, u16* __restrict__ xb,
                   u16* __restrict__ zc)
{
    const long long i = (long long)blockIdx.x * 256 + threadIdx.x;  // float4 index
    const float4 v = ((const float4*)x)[i];
    u16x4 b;
    b.x = to_bf16(v.x); b.y = to_bf16(v.y); b.z = to_bf16(v.z); b.w = to_bf16(v.w);
    ((u16x4*)xb)[i] = b;
    const long long flat = i * 4;
    const long long row = flat >> 12;        // / 4096
    const int col = (int)(flat & 4095);
    u16x4 tq;
    tq.x = to_bf16(tanhf(v.x)); tq.y = to_bf16(tanhf(v.y));
    tq.z = to_bf16(tanhf(v.z)); tq.w = to_bf16(tanhf(v.w));
    *(u16x4*)(zc + row * (long long)K_CAT + 1024 + col) = tq;
}

// ---------------------------------------------------------------------------
// Reparameterization: std was already computed by the ls-head GEMM epilogue
// (exp fused). Here: z = eps*std + mu, tanh(z) bf16 -> zc[:, 0:1024].
// ---------------------------------------------------------------------------
__global__ __launch_bounds__(256)
void reparam_kernel(const float* __restrict__ mu, const float* __restrict__ stdv,
                    const float* __restrict__ eps, u16* __restrict__ zc)
{
    const long long row = blockIdx.x;
    const int c = threadIdx.x * 4;
    const long long idx = row * 1024 + c;
    const float4 m = *(const float4*)(mu + idx);
    const float4 sd = *(const float4*)(stdv + idx);
    const float4 e = *(const float4*)(eps + idx);
    u16x4 t;
    t.x = to_bf16(tanhf(e.x * sd.x + m.x));
    t.y = to_bf16(tanhf(e.y * sd.y + m.y));
    t.z = to_bf16(tanhf(e.z * sd.z + m.z));
    t.w = to_bf16(tanhf(e.w * sd.w + m.w));
    *(u16x4*)(zc + row * (long long)K_CAT + c) = t;
}

// fp32 -> bf16 bulk convert (n4 = count of float4 quads)
__global__ __launch_bounds__(256)
void cvt_kernel(const float* __restrict__ src, u16* __restrict__ dst, long long n4)
{
    const long long i = (long long)blockIdx.x * 256 + threadIdx.x;
    if (i >= n4) return;
    const float4 v = ((const float4*)src)[i];
    u16x4 b;
    b.x = to_bf16(v.x); b.y = to_bf16(v.y); b.z = to_bf16(v.z); b.w = to_bf16(v.w);
    ((u16x4*)dst)[i] = b;
}

// Merged fp32->bf16 convert of the 4 pre-GEMM1 weight tensors (1 launch
// instead of 4). Segment boundaries in float4 quads:
//   W1: [0, 1048576) ; W2: [1048576, 1310720) ; Wmu: [1310720, 1572864) ;
//   Wls: [1572864, 1835008). Grid = 7168 blocks x 256.
__global__ __launch_bounds__(256)
void cvt4_kernel(const float* __restrict__ s0, u16* __restrict__ d0,
                 const float* __restrict__ s1, u16* __restrict__ d1,
                 const float* __restrict__ s2, u16* __restrict__ d2,
                 const float* __restrict__ s3, u16* __restrict__ d3)
{
    long long i = (long long)blockIdx.x * 256 + threadIdx.x;
    const float* s; u16* d;
    if (i < 1048576)      { s = s0; d = d0; }
    else if (i < 1310720) { s = s1; d = d1; i -= 1048576; }
    else if (i < 1572864) { s = s2; d = d2; i -= 1310720; }
    else                  { s = s3; d = d3; i -= 1572864; }
    const float4 v = ((const float4*)s)[i];
    u16x4 b;
    b.x = to_bf16(v.x); b.y = to_bf16(v.y); b.z = to_bf16(v.z); b.w = to_bf16(v.w);
    ((u16x4*)d)[i] = b;
}

extern "C" void kernel_launch(void* const* d_in, const int* in_sizes, int n_in,
                              void* d_out, int out_size, void* d_ws, size_t ws_size,
                              hipStream_t stream)
{
    const float* x   = (const float*)d_in[0];
    const float* eps = (const float*)d_in[1];
    const float* W1  = (const float*)d_in[2];
    const float* b1  = (const float*)d_in[3];
    const float* g1  = (const float*)d_in[4];
    const float* be1 = (const float*)d_in[5];
    const float* W2  = (const float*)d_in[6];
    const float* b2  = (const float*)d_in[7];
    const float* g2  = (const float*)d_in[8];
    const float* be2 = (const float*)d_in[9];
    const float* Wmu = (const float*)d_in[10];
    const float* bmu = (const float*)d_in[11];
    const float* Wls = (const float*)d_in[12];
    const float* bls = (const float*)d_in[13];
    const float* Wzw = (const float*)d_in[14];
    const float* bzw = (const float*)d_in[15];

    float* out  = (float*)d_out;                         // [8192,4096]
    float* mu   = out + (long long)M_TOT * D_OUT;        // [8192,1024]
    float* std_ = mu  + (long long)M_TOT * Z_DIM;        // [8192,1024]

    // workspace layout (bytes):
    char* ws = (char*)d_ws;
    u16*   xb   = (u16*)(ws);                  //  67,108,864  x bf16 [8192,4096]
    u16*   zc   = (u16*)(ws +  67108864);      //  83,886,080  concat bf16 [8192,5120]
    u16*   h1   = (u16*)(ws + 150994944);      //  16,777,216
    u16*   h2   = (u16*)(ws + 167772160);      //  16,777,216
    float* pre  = (float*)(ws + 184549376);    //  33,554,432  GEMM fp32 out [8192,1024]
    u16*   W1b  = (u16*)(ws + 218103808);      //   8,388,608
    u16*   W2b  = (u16*)(ws + 226492416);      //   2,097,152
    u16*   Wmub = (u16*)(ws + 228589568);      //   2,097,152
    u16*   Wlsb = (u16*)(ws + 230686720);      //   2,097,152
    u16*   Wzwb = (u16*)(ws);                  // reuses xb region after GEMM1 (42MB<=64MB)
    // total ws = 232,783,872 bytes

    // weight conversions (merged: 1 launch instead of 4)
    cvt4_kernel<<<7168, 256, 0, stream>>>(W1, W1b, W2, W2b, Wmu, Wmub, Wls, Wlsb);

    // x -> bf16 + tanh(x) into concat buffer right half
    prep_x_kernel<<<32768, 256, 0, stream>>>(x, xb, zc);

    // layer 1: pre = x @ W1^T + b1 ; h1 = tanh(LN(pre)) — 256x128-tile
    // kernel, grid (8,32) = 256 blocks = 1 block/CU, full chip.
    gemm128n<<<dim3(8, 32, 1), 512, 0, stream>>>(xb, W1b, b1, pre,
                                                 M_TOT, Z_DIM, D_IN);
    ln_tanh_kernel<<<8192, 256, 0, stream>>>(pre, g1, be1, h1);

    // Wzw conversion AFTER gemm1 (Wzwb aliases xb)
    cvt_kernel<<<20480, 256, 0, stream>>>(Wzw, Wzwb, 5242880);

    // layer 2
    gemm128n<<<dim3(8, 32, 1), 512, 0, stream>>>(h1, W2b, b2, pre,
                                                 M_TOT, Z_DIM, Z_DIM);
    ln_tanh_kernel<<<8192, 256, 0, stream>>>(pre, g2, be2, h2);

    // mu / logsigma heads (dual GEMM via gridDim.z) — verified 256^2 kernel,
    // 256 blocks = full chip. EXPLS=true: the z=1 (ls) epilogue writes
    // std = exp(0.5*(acc+bias)) directly into the std_ output slot.
    gemm256<true><<<dim3(4, 32, 2), 512, 0, stream>>>(h2, Wmub, Wlsb, bmu, bls,
                                                      mu, std_,
                                                      M_TOT, Z_DIM, Z_DIM);

    // reparameterize: tanh(eps*std + mu) -> concat left half
    reparam_kernel<<<8192, 256, 0, stream>>>(mu, std_, eps, zc);

    // final projection: out = tanh([z,x]) @ Wzw^T + bzw — the dominant GEMM
    // (343.6 GFLOP), on the verified 8-phase 256^2 schedule.
    gemm256<false><<<dim3(16, 32, 1), 512, 0, stream>>>(zc, Wzwb, Wzwb, bzw, bzw,
                                                        out, out,
                                                        M_TOT, D_OUT, K_CAT);
}